// Round 2
// baseline (38992.090 us; speedup 1.0000x reference)
//
#include <hip/hip_runtime.h>
#include <cstddef>

// Problem constants (match reference)
#define NN 20000
#define EE 400000
#define TT 1500000
#define BB 128
#define HH 128
#define INTD 64
#define OUT_EMB 256
#define SBF_DIM 42
#define NRAD 6

__device__ __forceinline__ float silu_f(float v) {
    return v / (1.0f + __expf(-v));
}

// ---------------------------------------------------------------------------
// Generic tiled fp32 GEMM: out = [silu](A (+A2) @ W + bias) [+ res]
// A: [M,K] row-major, W: [K,N] row-major. M must be divisible by 32.
// Tile: 32 rows x 64 cols per block (256 threads, 2 rows x 4 cols/thread),
// K processed in chunks of <=128 staged in LDS.
// NOTE: out must NOT alias A or A2 when N > 64 (multi-chunk re-stages A).
// ---------------------------------------------------------------------------
template <int K>
__launch_bounds__(256)
__global__ void gemm_k(const float* __restrict__ A, const float* __restrict__ A2,
                       const float* __restrict__ W, const float* __restrict__ bias,
                       const float* __restrict__ res, float* __restrict__ out,
                       int N, int act) {
    constexpr int KC = (K <= 128) ? K : 128;   // K-chunk
    __shared__ float As[32][KC + 1];
    __shared__ float Ws[KC * 64];

    const int tid = threadIdx.x;
    const size_t row0 = (size_t)blockIdx.x * 32;
    const int tx = tid & 15, ty = tid >> 4;
    const int c0 = tx * 4;       // col within 64-wide chunk
    const int r0 = ty * 2;       // rows r0, r0+1

    for (int nc0 = 0; nc0 < N; nc0 += 64) {
        float acc[2][4] = {{0.f, 0.f, 0.f, 0.f}, {0.f, 0.f, 0.f, 0.f}};
        for (int kc0 = 0; kc0 < K; kc0 += KC) {
            __syncthreads();
            // stage A tile (32 x KC)
            for (int idx = tid; idx < 32 * KC / 4; idx += 256) {
                int r = idx / (KC / 4);
                int kk = (idx % (KC / 4)) * 4;
                float4 v = *(const float4*)(A + (row0 + r) * K + kc0 + kk);
                if (A2) {
                    float4 b = *(const float4*)(A2 + (row0 + r) * K + kc0 + kk);
                    v.x += b.x; v.y += b.y; v.z += b.z; v.w += b.w;
                }
                As[r][kk] = v.x; As[r][kk + 1] = v.y;
                As[r][kk + 2] = v.z; As[r][kk + 3] = v.w;
            }
            // stage W chunk (KC x 64)
            for (int idx = tid; idx < KC * 16; idx += 256) {
                int k = idx >> 4;
                int cc = (idx & 15) * 4;
                *(float4*)&Ws[k * 64 + cc] =
                    *(const float4*)(W + (size_t)(kc0 + k) * N + nc0 + cc);
            }
            __syncthreads();
#pragma unroll 4
            for (int k = 0; k < KC; ++k) {
                float a0 = As[r0][k];
                float a1 = As[r0 + 1][k];
                float4 w = *(const float4*)&Ws[k * 64 + c0];
                acc[0][0] += a0 * w.x; acc[0][1] += a0 * w.y;
                acc[0][2] += a0 * w.z; acc[0][3] += a0 * w.w;
                acc[1][0] += a1 * w.x; acc[1][1] += a1 * w.y;
                acc[1][2] += a1 * w.z; acc[1][3] += a1 * w.w;
            }
        }
        // epilogue (vectorized float4)
#pragma unroll
        for (int i = 0; i < 2; ++i) {
            size_t off = (row0 + r0 + i) * N + nc0 + c0;
            float4 v = make_float4(acc[i][0], acc[i][1], acc[i][2], acc[i][3]);
            if (bias) {
                float4 b = *(const float4*)(bias + nc0 + c0);
                v.x += b.x; v.y += b.y; v.z += b.z; v.w += b.w;
            }
            if (act) {
                v.x = silu_f(v.x); v.y = silu_f(v.y);
                v.z = silu_f(v.z); v.w = silu_f(v.w);
            }
            if (res) {
                float4 r = *(const float4*)(res + off);
                v.x += r.x; v.y += r.y; v.z += r.z; v.w += r.w;
            }
            *(float4*)(out + off) = v;
        }
    }
}

// C_rbf12[l] = We_rbf1[l] (6x8) @ We_rbf2[l] (8x128) -> [6,128]
__global__ void combine_rbf(const float* __restrict__ W1, const float* __restrict__ W2,
                            float* __restrict__ C) {
    int l = blockIdx.x;
    const float* w1 = W1 + l * 48;
    const float* w2 = W2 + l * 1024;
    float* c = C + l * 768;
    for (int idx = threadIdx.x; idx < 768; idx += 256) {
        int j = idx >> 7, h = idx & 127;
        float s = 0.f;
#pragma unroll
        for (int p = 0; p < 8; ++p) s += w1[j * 8 + p] * w2[p * 128 + h];
        c[idx] = s;
    }
}

// buf[e][h] *= sum_j rbf[e][j] * C[j][h]
__global__ void mul_r(const float* __restrict__ rbf, const float* __restrict__ C,
                      float* __restrict__ buf) {
    int idx = blockIdx.x * 256 + threadIdx.x;   // over E*128
    int h = idx & 127;
    int e = idx >> 7;
    const float* rr = rbf + (size_t)e * NRAD;
    float r = 0.f;
#pragma unroll
    for (int j = 0; j < NRAD; ++j) r += rr[j] * C[j * 128 + h];
    buf[idx] *= r;
}

// Triplet: agg[idx_ji[t]] += xkj[idx_kj[t]] * ((sbf[t] @ W1) @ W2)
__launch_bounds__(256)
__global__ void triplet_kernel(const float* __restrict__ sbf, const float* __restrict__ Wsbf1,
                               const float* __restrict__ Wsbf2, const float* __restrict__ xkj,
                               const int* __restrict__ idx_kj, const int* __restrict__ idx_ji,
                               float* __restrict__ agg) {
    __shared__ float W1[SBF_DIM * 8];
    __shared__ float W2[8 * INTD];
    int tid = threadIdx.x;
    for (int i = tid; i < SBF_DIM * 8; i += 256) W1[i] = Wsbf1[i];
    for (int i = tid; i < 8 * INTD; i += 256) W2[i] = Wsbf2[i];
    __syncthreads();
    int t = blockIdx.x * 256 + tid;
    if (t >= TT) return;

    const float* srow = sbf + (size_t)t * SBF_DIM;
    float sb[SBF_DIM];
#pragma unroll
    for (int j = 0; j < SBF_DIM; ++j) sb[j] = srow[j];
    float p8[8];
#pragma unroll
    for (int p = 0; p < 8; ++p) {
        float s = 0.f;
#pragma unroll
        for (int j = 0; j < SBF_DIM; ++j) s += sb[j] * W1[j * 8 + p];
        p8[p] = s;
    }
    const float* xr = xkj + (size_t)idx_kj[t] * INTD;
    float* ar = agg + (size_t)idx_ji[t] * INTD;
#pragma unroll
    for (int c = 0; c < INTD; c += 4) {
        float4 x4 = *(const float4*)(xr + c);
        float s0 = 0.f, s1 = 0.f, s2 = 0.f, s3 = 0.f;
#pragma unroll
        for (int p = 0; p < 8; ++p) {
            float pv = p8[p];
            s0 += pv * W2[p * INTD + c];
            s1 += pv * W2[p * INTD + c + 1];
            s2 += pv * W2[p * INTD + c + 2];
            s3 += pv * W2[p * INTD + c + 3];
        }
        atomicAdd(ar + c,     x4.x * s0);
        atomicAdd(ar + c + 1, x4.y * s1);
        atomicAdd(ar + c + 2, x4.z * s2);
        atomicAdd(ar + c + 3, x4.w * s3);
    }
}

// vseg[i[e]][h] += (rbf[e] @ W)[h] * e1[e][h]
__global__ void e2_scatter(const float* __restrict__ rbf, const float* __restrict__ W,
                           const float* __restrict__ e1, const int* __restrict__ iidx,
                           float* __restrict__ vseg) {
    int idx = blockIdx.x * 256 + threadIdx.x;   // over E*128
    int h = idx & 127;
    int e = idx >> 7;
    const float* rr = rbf + (size_t)e * NRAD;
    float r = 0.f;
#pragma unroll
    for (int j = 0; j < NRAD; ++j) r += rr[j] * W[j * 128 + h];
    atomicAdd(&vseg[(size_t)iidx[e] * 128 + h], r * e1[idx]);
}

// u0[batch[n]][h] += v[n][h]
__global__ void scatter_u0(const float* __restrict__ v, const int* __restrict__ batch,
                           float* __restrict__ u0) {
    int idx = blockIdx.x * 256 + threadIdx.x;   // over N*128
    int h = idx & 127;
    int n = idx >> 7;
    atomicAdd(&u0[(size_t)batch[n] * 128 + h], v[idx]);
}

// sbatch[batch[n]] += dot(vn[n], Wv_out)   (one wave per node)
__launch_bounds__(256)
__global__ void vout_scatter(const float* __restrict__ vn, const float* __restrict__ Wv_out,
                             const int* __restrict__ batch, float* __restrict__ sbatch) {
    int wave = threadIdx.x >> 6, lane = threadIdx.x & 63;
    int n = blockIdx.x * 4 + wave;
    if (n >= NN) return;
    const float* row = vn + (size_t)n * OUT_EMB;
    float s = 0.f;
#pragma unroll
    for (int k = lane; k < OUT_EMB; k += 64) s += row[k] * Wv_out[k];
#pragma unroll
    for (int off = 32; off > 0; off >>= 1) s += __shfl_down(s, off);
    if (lane == 0) atomicAdd(&sbatch[batch[n]], s);
}

__global__ void final_out(const float* __restrict__ u0, const float* __restrict__ sb,
                          float* __restrict__ out) {
    int idx = blockIdx.x * 256 + threadIdx.x;   // B*128
    out[idx] = u0[idx] + sb[idx >> 7];
}

extern "C" void kernel_launch(void* const* d_in, const int* in_sizes, int n_in,
                              void* d_out, int out_size, void* d_ws, size_t ws_size,
                              hipStream_t stream) {
    const float* x         = (const float*)d_in[0];
    const float* edge_attr = (const float*)d_in[1];
    const float* rbf       = (const float*)d_in[2];
    const float* sbf       = (const float*)d_in[3];
    const int*   iidx      = (const int*)d_in[4];
    const int*   idx_kj    = (const int*)d_in[5];
    const int*   idx_ji    = (const int*)d_in[6];
    const int*   batch     = (const int*)d_in[7];
    const float* W_node    = (const float*)d_in[8];
    const float* W_edge    = (const float*)d_in[9];
    const float* We_rbf1   = (const float*)d_in[10];
    const float* We_rbf2   = (const float*)d_in[11];
    const float* We_sbf1   = (const float*)d_in[12];
    const float* We_sbf2   = (const float*)d_in[13];
    const float* We_rbf    = (const float*)d_in[14];
    const float* We_kj     = (const float*)d_in[15];
    const float* be_kj     = (const float*)d_in[16];
    const float* We_ji     = (const float*)d_in[17];
    const float* be_ji     = (const float*)d_in[18];
    const float* We_down   = (const float*)d_in[19];
    const float* We_up     = (const float*)d_in[20];
    const float* We_cat    = (const float*)d_in[21];
    const float* Wres_b    = (const float*)d_in[22];
    const float* bres_b    = (const float*)d_in[23];
    const float* We_lin    = (const float*)d_in[24];
    const float* be_lin    = (const float*)d_in[25];
    const float* Wres_a    = (const float*)d_in[26];
    const float* bres_a    = (const float*)d_in[27];
    const float* Wv_up     = (const float*)d_in[28];
    const float* bv_up     = (const float*)d_in[29];
    const float* Wv_lins   = (const float*)d_in[30];
    const float* bv_lins   = (const float*)d_in[31];
    const float* Wv_out    = (const float*)d_in[32];
    float* out = (float*)d_out;

    // workspace layout (floats)
    float* ws   = (float*)d_ws;
    float* e1   = ws;                                  // E*128
    float* buf1 = e1 + (size_t)EE * HH;                // E*128
    float* buf2 = buf1 + (size_t)EE * HH;              // E*128
    float* bufC = buf2 + (size_t)EE * HH;              // E*64 (x_kj_down)
    float* bufD = bufC + (size_t)EE * INTD;            // E*64 (triplet agg)
    float* tail = bufD + (size_t)EE * INTD;
    float* u0     = tail;                              // B*128
    float* sbatch = u0 + BB * HH;                      // 256 (padded)
    float* Crbf   = sbatch + 256;                      // 4*6*128
    // catbuf: E*128 spanning bufC..bufD (both dead once We_up consumed bufD)
    float* catbuf = bufC;
    // aliased node-stage buffers (bufC region is dead when these are live)
    float* vseg = bufC;                                // N*128
    float* vn1  = bufC + (size_t)NN * HH;              // N*256
    float* vn2  = vn1 + (size_t)NN * OUT_EMB;          // N*256

    hipMemsetAsync(u0, 0, (size_t)BB * HH * sizeof(float), stream);
    hipMemsetAsync(sbatch, 0, 256 * sizeof(float), stream);
    combine_rbf<<<4, 256, 0, stream>>>(We_rbf1, We_rbf2, Crbf);

    // e1 = edge_attr @ W_edge
    gemm_k<12><<<EE / 32, 256, 0, stream>>>(edge_attr, nullptr, W_edge, nullptr, nullptr, e1, HH, 0);
    // v = x @ W_node -> vseg; u0 = seg(v, batch)
    gemm_k<48><<<NN / 32, 256, 0, stream>>>(x, nullptr, W_node, nullptr, nullptr, vseg, HH, 0);
    scatter_u0<<<NN * HH / 256, 256, 0, stream>>>(vseg, batch, u0);

    for (int l = 0; l < 4; ++l) {
        // x_ji, x_kj
        gemm_k<128><<<EE / 32, 256, 0, stream>>>(e1, nullptr, We_ji + (size_t)l * HH * HH,
                                                 be_ji + l * HH, nullptr, buf1, HH, 1);
        gemm_k<128><<<EE / 32, 256, 0, stream>>>(e1, nullptr, We_kj + (size_t)l * HH * HH,
                                                 be_kj + l * HH, nullptr, buf2, HH, 1);
        // x_kj *= r
        mul_r<<<EE * HH / 256, 256, 0, stream>>>(rbf, Crbf + l * 768, buf2);
        // down-projection
        gemm_k<128><<<EE / 32, 256, 0, stream>>>(buf2, nullptr, We_down + (size_t)l * HH * INTD,
                                                 nullptr, nullptr, bufC, INTD, 1);
        // triplet gather/scatter
        hipMemsetAsync(bufD, 0, (size_t)EE * INTD * sizeof(float), stream);
        triplet_kernel<<<(TT + 255) / 256, 256, 0, stream>>>(
            sbf, We_sbf1 + l * SBF_DIM * 8, We_sbf2 + l * 8 * INTD, bufC, idx_kj, idx_ji, bufD);
        // up-projection
        gemm_k<64><<<EE / 32, 256, 0, stream>>>(bufD, nullptr, We_up + (size_t)l * INTD * HH,
                                                nullptr, nullptr, buf2, HH, 1);
        // e = silu((x_ji + x_kj) @ We_cat) -> catbuf (bufC..bufD now dead;
        // CANNOT write buf1/buf2 in-place: N=128 re-stages A per 64-col chunk)
        gemm_k<128><<<EE / 32, 256, 0, stream>>>(buf1, buf2, We_cat + (size_t)l * HH * HH,
                                                 nullptr, nullptr, catbuf, HH, 1);
        // residual block before skip (NBS=1): e = catbuf + silu(silu(catbuf@W0+b0)@W1+b1) -> buf1
        gemm_k<128><<<EE / 32, 256, 0, stream>>>(catbuf, nullptr, Wres_b + (size_t)(l * 2 + 0) * HH * HH,
                                                 bres_b + (l * 2 + 0) * HH, nullptr, buf2, HH, 1);
        gemm_k<128><<<EE / 32, 256, 0, stream>>>(buf2, nullptr, Wres_b + (size_t)(l * 2 + 1) * HH * HH,
                                                 bres_b + (l * 2 + 1) * HH, catbuf, buf1, HH, 1);
        // e = silu(e @ We_lin + b) + e1   (into e1)
        gemm_k<128><<<EE / 32, 256, 0, stream>>>(buf1, nullptr, We_lin + (size_t)l * HH * HH,
                                                 be_lin + l * HH, e1, e1, HH, 1);
        // residual blocks after skip (NAS=2)
        for (int r = 0; r < 2; ++r) {
            gemm_k<128><<<EE / 32, 256, 0, stream>>>(
                e1, nullptr, Wres_a + (size_t)((l * 2 + r) * 2 + 0) * HH * HH,
                bres_a + ((l * 2 + r) * 2 + 0) * HH, nullptr, buf2, HH, 1);
            gemm_k<128><<<EE / 32, 256, 0, stream>>>(
                buf2, nullptr, Wres_a + (size_t)((l * 2 + r) * 2 + 1) * HH * HH,
                bres_a + ((l * 2 + r) * 2 + 1) * HH, e1, e1, HH, 1);
        }
        // e2 = (rbf @ We_rbf) * e1, scattered to nodes
        hipMemsetAsync(vseg, 0, (size_t)NN * HH * sizeof(float), stream);
        e2_scatter<<<EE * HH / 256, 256, 0, stream>>>(rbf, We_rbf + l * NRAD * HH, e1, iidx, vseg);
        // vn = vseg @ Wv_up + b (no act)
        gemm_k<128><<<NN / 32, 256, 0, stream>>>(vseg, nullptr, Wv_up + (size_t)l * HH * OUT_EMB,
                                                 bv_up + l * OUT_EMB, nullptr, vn1, OUT_EMB, 0);
        // 3 silu lins (256x256)
        gemm_k<256><<<NN / 32, 256, 0, stream>>>(vn1, nullptr, Wv_lins + (size_t)(l * 3 + 0) * 65536,
                                                 bv_lins + (l * 3 + 0) * 256, nullptr, vn2, OUT_EMB, 1);
        gemm_k<256><<<NN / 32, 256, 0, stream>>>(vn2, nullptr, Wv_lins + (size_t)(l * 3 + 1) * 65536,
                                                 bv_lins + (l * 3 + 1) * 256, nullptr, vn1, OUT_EMB, 1);
        gemm_k<256><<<NN / 32, 256, 0, stream>>>(vn1, nullptr, Wv_lins + (size_t)(l * 3 + 2) * 65536,
                                                 bv_lins + (l * 3 + 2) * 256, nullptr, vn2, OUT_EMB, 1);
        // vn @ Wv_out -> per-batch scalar accumulation
        vout_scatter<<<NN / 4, 256, 0, stream>>>(vn2, Wv_out + l * OUT_EMB, batch, sbatch);
    }
    final_out<<<BB * HH / 256, 256, 0, stream>>>(u0, sbatch, out);
}

// Round 5
// 19726.152 us; speedup vs baseline: 1.9767x; 1.9767x over previous
//
#include <hip/hip_runtime.h>
#include <cstddef>

// Problem constants (match reference)
#define NN 20000
#define EE 400000
#define TT 1500000
#define BB 128
#define HH 128
#define INTD 64
#define OUT_EMB 256
#define SBF_DIM 42
#define NRAD 6

__device__ __forceinline__ float silu_f(float v) {
    return v / (1.0f + __expf(-v));
}

// ---------------------------------------------------------------------------
// Generic tiled fp32 GEMM: out = [silu](A (+A2) @ W + bias) [+ res]
// NOTE: out must NOT alias A or A2 when N > 64 (multi-chunk re-stages A).
// ---------------------------------------------------------------------------
template <int K>
__launch_bounds__(256)
__global__ void gemm_k(const float* __restrict__ A, const float* __restrict__ A2,
                       const float* __restrict__ W, const float* __restrict__ bias,
                       const float* __restrict__ res, float* __restrict__ out,
                       int N, int act) {
    constexpr int KC = (K <= 128) ? K : 128;   // K-chunk
    __shared__ float As[32][KC + 1];
    __shared__ float Ws[KC * 64];

    const int tid = threadIdx.x;
    const size_t row0 = (size_t)blockIdx.x * 32;
    const int tx = tid & 15, ty = tid >> 4;
    const int c0 = tx * 4;       // col within 64-wide chunk
    const int r0 = ty * 2;       // rows r0, r0+1

    for (int nc0 = 0; nc0 < N; nc0 += 64) {
        float acc[2][4] = {{0.f, 0.f, 0.f, 0.f}, {0.f, 0.f, 0.f, 0.f}};
        for (int kc0 = 0; kc0 < K; kc0 += KC) {
            __syncthreads();
            for (int idx = tid; idx < 32 * KC / 4; idx += 256) {
                int r = idx / (KC / 4);
                int kk = (idx % (KC / 4)) * 4;
                float4 v = *(const float4*)(A + (row0 + r) * K + kc0 + kk);
                if (A2) {
                    float4 b = *(const float4*)(A2 + (row0 + r) * K + kc0 + kk);
                    v.x += b.x; v.y += b.y; v.z += b.z; v.w += b.w;
                }
                As[r][kk] = v.x; As[r][kk + 1] = v.y;
                As[r][kk + 2] = v.z; As[r][kk + 3] = v.w;
            }
            for (int idx = tid; idx < KC * 16; idx += 256) {
                int k = idx >> 4;
                int cc = (idx & 15) * 4;
                *(float4*)&Ws[k * 64 + cc] =
                    *(const float4*)(W + (size_t)(kc0 + k) * N + nc0 + cc);
            }
            __syncthreads();
#pragma unroll 4
            for (int k = 0; k < KC; ++k) {
                float a0 = As[r0][k];
                float a1 = As[r0 + 1][k];
                float4 w = *(const float4*)&Ws[k * 64 + c0];
                acc[0][0] += a0 * w.x; acc[0][1] += a0 * w.y;
                acc[0][2] += a0 * w.z; acc[0][3] += a0 * w.w;
                acc[1][0] += a1 * w.x; acc[1][1] += a1 * w.y;
                acc[1][2] += a1 * w.z; acc[1][3] += a1 * w.w;
            }
        }
#pragma unroll
        for (int i = 0; i < 2; ++i) {
            size_t off = (row0 + r0 + i) * N + nc0 + c0;
            float4 v = make_float4(acc[i][0], acc[i][1], acc[i][2], acc[i][3]);
            if (bias) {
                float4 b = *(const float4*)(bias + nc0 + c0);
                v.x += b.x; v.y += b.y; v.z += b.z; v.w += b.w;
            }
            if (act) {
                v.x = silu_f(v.x); v.y = silu_f(v.y);
                v.z = silu_f(v.z); v.w = silu_f(v.w);
            }
            if (res) {
                float4 r = *(const float4*)(res + off);
                v.x += r.x; v.y += r.y; v.z += r.z; v.w += r.w;
            }
            *(float4*)(out + off) = v;
        }
    }
}

// C_rbf12[l] = We_rbf1[l] (6x8) @ We_rbf2[l] (8x128) -> [6,128]
__global__ void combine_rbf(const float* __restrict__ W1, const float* __restrict__ W2,
                            float* __restrict__ C) {
    int l = blockIdx.x;
    const float* w1 = W1 + l * 48;
    const float* w2 = W2 + l * 1024;
    float* c = C + l * 768;
    for (int idx = threadIdx.x; idx < 768; idx += 256) {
        int j = idx >> 7, h = idx & 127;
        float s = 0.f;
#pragma unroll
        for (int p = 0; p < 8; ++p) s += w1[j * 8 + p] * w2[p * 128 + h];
        c[idx] = s;
    }
}

// buf[e][h] *= sum_j rbf[e][j] * C[j][h]
__global__ void mul_r(const float* __restrict__ rbf, const float* __restrict__ C,
                      float* __restrict__ buf) {
    int idx = blockIdx.x * 256 + threadIdx.x;   // over E*128
    int h = idx & 127;
    int e = idx >> 7;
    const float* rr = rbf + (size_t)e * NRAD;
    float r = 0.f;
#pragma unroll
    for (int j = 0; j < NRAD; ++j) r += rr[j] * C[j * 128 + h];
    buf[idx] *= r;
}

// ------------------------- CSR build (once per call) -------------------------
__global__ void hist_kernel(const int* __restrict__ idx, int n, int* __restrict__ cnt) {
    int t = blockIdx.x * 256 + threadIdx.x;
    if (t < n) atomicAdd(&cnt[idx[t]], 1);
}

// single-block chunked exclusive scan: offs[0..n] (offs[n]=total), cur=copy
__launch_bounds__(1024)
__global__ void scan_kernel(const int* __restrict__ cnt, int n,
                            int* __restrict__ offs, int* __restrict__ cur) {
    __shared__ int tmp[1024];
    __shared__ int carry_s;
    if (threadIdx.x == 0) carry_s = 0;
    __syncthreads();
    for (int base = 0; base < n; base += 1024) {
        int i = base + threadIdx.x;
        int v = (i < n) ? cnt[i] : 0;
        tmp[threadIdx.x] = v;
        __syncthreads();
        for (int d = 1; d < 1024; d <<= 1) {
            int t = (threadIdx.x >= d) ? tmp[threadIdx.x - d] : 0;
            __syncthreads();
            tmp[threadIdx.x] += t;
            __syncthreads();
        }
        int excl = tmp[threadIdx.x] - v + carry_s;
        if (i < n) { offs[i] = excl; cur[i] = excl; }
        __syncthreads();
        if (threadIdx.x == 1023) carry_s += tmp[1023];
        __syncthreads();
    }
    if (threadIdx.x == 0) offs[n] = carry_s;
}

__global__ void fill_kernel(const int* __restrict__ idx, int n,
                            int* __restrict__ cur, int* __restrict__ lst) {
    int t = blockIdx.x * 256 + threadIdx.x;
    if (t < n) {
        int p = atomicAdd(&cur[idx[t]], 1);
        lst[p] = t;
    }
}

// ------------------------ triplet stage (gather form) ------------------------
// p8[t][p] = sum_j sbf[t][j] * W1[j][p]
// 128 threads / 128 rows per block: LDS = 128*43*4 + 42*8*4 = ~23 KB (fits).
__launch_bounds__(128)
__global__ void p8_kernel(const float* __restrict__ sbf, const float* __restrict__ W1,
                          float* __restrict__ p8) {
    __shared__ float S[128 * 43];
    __shared__ float Wl[SBF_DIM * 8];
    int tid = threadIdx.x;
    for (int i = tid; i < SBF_DIM * 8; i += 128) Wl[i] = W1[i];
    size_t base = (size_t)blockIdx.x * 128;
    int rows = (TT - base) < 128 ? (int)(TT - base) : 128;
    const float* src = sbf + base * SBF_DIM;
    for (int i = tid; i < rows * SBF_DIM; i += 128) {
        int r = i / SBF_DIM, j = i - r * SBF_DIM;
        S[r * 43 + j] = src[i];
    }
    __syncthreads();
    if (tid >= rows) return;
    float pv[8] = {0.f, 0.f, 0.f, 0.f, 0.f, 0.f, 0.f, 0.f};
    for (int j = 0; j < SBF_DIM; ++j) {
        float sv = S[tid * 43 + j];
#pragma unroll
        for (int p = 0; p < 8; ++p) pv[p] += sv * Wl[j * 8 + p];
    }
    float4* o = (float4*)(p8 + (base + tid) * 8);
    o[0] = make_float4(pv[0], pv[1], pv[2], pv[3]);
    o[1] = make_float4(pv[4], pv[5], pv[6], pv[7]);
}

// one wave per edge: agg[e][c] = sum_{t in bucket(e)} (p8[t]·W2[:,c]) * xkj[idx_kj[t]][c]
__launch_bounds__(256)
__global__ void triplet_gather(const float* __restrict__ p8, const float* __restrict__ W2,
                               const float* __restrict__ xkj, const int* __restrict__ idx_kj,
                               const int* __restrict__ offsT, const int* __restrict__ tlist,
                               float* __restrict__ agg) {
    int lane = threadIdx.x & 63;
    int wv = threadIdx.x >> 6;
    int e = blockIdx.x * 4 + wv;
    if (e >= EE) return;
    float w2c[8];
#pragma unroll
    for (int p = 0; p < 8; ++p) w2c[p] = W2[p * INTD + lane];
    int b = offsT[e], en = offsT[e + 1];
    float acc = 0.f;
    for (int q = b; q < en; ++q) {
        int t = tlist[q];
        int k = idx_kj[t];
        const float4* pr = (const float4*)(p8 + (size_t)t * 8);
        float4 p0 = pr[0], p1 = pr[1];
        float s = p0.x * w2c[0] + p0.y * w2c[1] + p0.z * w2c[2] + p0.w * w2c[3]
                + p1.x * w2c[4] + p1.y * w2c[5] + p1.z * w2c[6] + p1.w * w2c[7];
        acc += s * xkj[(size_t)k * INTD + lane];
    }
    agg[(size_t)e * INTD + lane] = acc;
}

// ------------------------- e2 stage (gather form) ---------------------------
// vseg[n][h] = sum_{e in bucket(n)} (rbf[e]@Wr)[h] * e1[e][h]   (128 thr/node)
// Wr is We_rbf[l]: [6,128] row-major (the STANDALONE rbf projection, not Crbf!)
__launch_bounds__(256)
__global__ void e2_gather(const float* __restrict__ rbf, const float* __restrict__ Wr,
                          const float* __restrict__ e1, const int* __restrict__ offsE,
                          const int* __restrict__ elist, float* __restrict__ vseg) {
    int h = threadIdx.x & 127;
    int sub = threadIdx.x >> 7;
    int n = blockIdx.x * 2 + sub;
    if (n >= NN) return;
    float c0 = Wr[0 * 128 + h], c1 = Wr[1 * 128 + h], c2 = Wr[2 * 128 + h],
          c3 = Wr[3 * 128 + h], c4 = Wr[4 * 128 + h], c5 = Wr[5 * 128 + h];
    int b = offsE[n], en = offsE[n + 1];
    float acc = 0.f;
    for (int q = b; q < en; ++q) {
        int e = elist[q];
        const float* rr = rbf + (size_t)e * NRAD;
        float r = rr[0] * c0 + rr[1] * c1 + rr[2] * c2 + rr[3] * c3 + rr[4] * c4 + rr[5] * c5;
        acc += r * e1[(size_t)e * 128 + h];
    }
    vseg[(size_t)n * 128 + h] = acc;
}

// u0[batch[n]][h] += v[n][h]
__global__ void scatter_u0(const float* __restrict__ v, const int* __restrict__ batch,
                           float* __restrict__ u0) {
    int idx = blockIdx.x * 256 + threadIdx.x;   // over N*128
    int h = idx & 127;
    int n = idx >> 7;
    atomicAdd(&u0[(size_t)batch[n] * 128 + h], v[idx]);
}

// sbatch[batch[n]] += dot(vn[n], Wv_out)   (one wave per node)
__launch_bounds__(256)
__global__ void vout_scatter(const float* __restrict__ vn, const float* __restrict__ Wv_out,
                             const int* __restrict__ batch, float* __restrict__ sbatch) {
    int wave = threadIdx.x >> 6, lane = threadIdx.x & 63;
    int n = blockIdx.x * 4 + wave;
    if (n >= NN) return;
    const float* row = vn + (size_t)n * OUT_EMB;
    float s = 0.f;
#pragma unroll
    for (int k = lane; k < OUT_EMB; k += 64) s += row[k] * Wv_out[k];
#pragma unroll
    for (int off = 32; off > 0; off >>= 1) s += __shfl_down(s, off);
    if (lane == 0) atomicAdd(&sbatch[batch[n]], s);
}

__global__ void final_out(const float* __restrict__ u0, const float* __restrict__ sb,
                          float* __restrict__ out) {
    int idx = blockIdx.x * 256 + threadIdx.x;   // B*128
    out[idx] = u0[idx] + sb[idx >> 7];
}

extern "C" void kernel_launch(void* const* d_in, const int* in_sizes, int n_in,
                              void* d_out, int out_size, void* d_ws, size_t ws_size,
                              hipStream_t stream) {
    const float* x         = (const float*)d_in[0];
    const float* edge_attr = (const float*)d_in[1];
    const float* rbf       = (const float*)d_in[2];
    const float* sbf       = (const float*)d_in[3];
    const int*   iidx      = (const int*)d_in[4];
    const int*   idx_kj    = (const int*)d_in[5];
    const int*   idx_ji    = (const int*)d_in[6];
    const int*   batch     = (const int*)d_in[7];
    const float* W_node    = (const float*)d_in[8];
    const float* W_edge    = (const float*)d_in[9];
    const float* We_rbf1   = (const float*)d_in[10];
    const float* We_rbf2   = (const float*)d_in[11];
    const float* We_sbf1   = (const float*)d_in[12];
    const float* We_sbf2   = (const float*)d_in[13];
    const float* We_rbf    = (const float*)d_in[14];
    const float* We_kj     = (const float*)d_in[15];
    const float* be_kj     = (const float*)d_in[16];
    const float* We_ji     = (const float*)d_in[17];
    const float* be_ji     = (const float*)d_in[18];
    const float* We_down   = (const float*)d_in[19];
    const float* We_up     = (const float*)d_in[20];
    const float* We_cat    = (const float*)d_in[21];
    const float* Wres_b    = (const float*)d_in[22];
    const float* bres_b    = (const float*)d_in[23];
    const float* We_lin    = (const float*)d_in[24];
    const float* be_lin    = (const float*)d_in[25];
    const float* Wres_a    = (const float*)d_in[26];
    const float* bres_a    = (const float*)d_in[27];
    const float* Wv_up     = (const float*)d_in[28];
    const float* bv_up     = (const float*)d_in[29];
    const float* Wv_lins   = (const float*)d_in[30];
    const float* bv_lins   = (const float*)d_in[31];
    const float* Wv_out    = (const float*)d_in[32];
    float* out = (float*)d_out;

    // workspace layout (floats)
    float* ws   = (float*)d_ws;
    float* e1   = ws;                                  // E*128
    float* buf1 = e1 + (size_t)EE * HH;                // E*128
    float* buf2 = buf1 + (size_t)EE * HH;              // E*128 (also aliased as p8 [T,8])
    float* bufC = buf2 + (size_t)EE * HH;              // E*64 (x_kj_down)
    float* bufD = bufC + (size_t)EE * INTD;            // E*64 (triplet agg)
    float* tail = bufD + (size_t)EE * INTD;
    float* u0     = tail;                              // B*128
    float* sbatch = u0 + BB * HH;                      // 256
    float* Crbf   = sbatch + 256;                      // 4*768
    int*   iptr   = (int*)(Crbf + 4 * 768);
    int* cntT  = iptr;               iptr += EE;       // triplet-bucket counts (per edge)
    int* offsT = iptr;               iptr += EE + 1;
    int* curT  = iptr;               iptr += EE;
    int* tlist = iptr;               iptr += TT;
    int* cntE  = iptr;               iptr += NN;       // edge-bucket counts (per node)
    int* offsE = iptr;               iptr += NN + 1;
    int* curE  = iptr;               iptr += NN;
    int* elist = iptr;               iptr += EE;
    float* p8 = buf2;                                  // [T,8] alias (dead x_kj*r window)
    float* catbuf = bufC;                              // E*128 spanning bufC..bufD
    float* vseg = bufC;                                // N*128
    float* vn1  = bufC + (size_t)NN * HH;              // N*256
    float* vn2  = vn1 + (size_t)NN * OUT_EMB;          // N*256

    hipMemsetAsync(u0, 0, (size_t)BB * HH * sizeof(float), stream);
    hipMemsetAsync(sbatch, 0, 256 * sizeof(float), stream);
    combine_rbf<<<4, 256, 0, stream>>>(We_rbf1, We_rbf2, Crbf);

    // ---- CSR builds (index structure is layer-independent) ----
    hipMemsetAsync(cntT, 0, EE * sizeof(int), stream);
    hipMemsetAsync(cntE, 0, NN * sizeof(int), stream);
    hist_kernel<<<(TT + 255) / 256, 256, 0, stream>>>(idx_ji, TT, cntT);
    hist_kernel<<<(EE + 255) / 256, 256, 0, stream>>>(iidx, EE, cntE);
    scan_kernel<<<1, 1024, 0, stream>>>(cntT, EE, offsT, curT);
    scan_kernel<<<1, 1024, 0, stream>>>(cntE, NN, offsE, curE);
    fill_kernel<<<(TT + 255) / 256, 256, 0, stream>>>(idx_ji, TT, curT, tlist);
    fill_kernel<<<(EE + 255) / 256, 256, 0, stream>>>(iidx, EE, curE, elist);

    // e1 = edge_attr @ W_edge
    gemm_k<12><<<EE / 32, 256, 0, stream>>>(edge_attr, nullptr, W_edge, nullptr, nullptr, e1, HH, 0);
    // v = x @ W_node -> vseg; u0 = seg(v, batch)
    gemm_k<48><<<NN / 32, 256, 0, stream>>>(x, nullptr, W_node, nullptr, nullptr, vseg, HH, 0);
    scatter_u0<<<NN * HH / 256, 256, 0, stream>>>(vseg, batch, u0);

    for (int l = 0; l < 4; ++l) {
        // x_ji, x_kj
        gemm_k<128><<<EE / 32, 256, 0, stream>>>(e1, nullptr, We_ji + (size_t)l * HH * HH,
                                                 be_ji + l * HH, nullptr, buf1, HH, 1);
        gemm_k<128><<<EE / 32, 256, 0, stream>>>(e1, nullptr, We_kj + (size_t)l * HH * HH,
                                                 be_kj + l * HH, nullptr, buf2, HH, 1);
        mul_r<<<EE * HH / 256, 256, 0, stream>>>(rbf, Crbf + l * 768, buf2);
        // down-projection buf2 -> bufC
        gemm_k<128><<<EE / 32, 256, 0, stream>>>(buf2, nullptr, We_down + (size_t)l * HH * INTD,
                                                 nullptr, nullptr, bufC, INTD, 1);
        // triplet stage: p8 = sbf @ We_sbf1 (into dead buf2), then CSR gather
        p8_kernel<<<(TT + 127) / 128, 128, 0, stream>>>(sbf, We_sbf1 + l * SBF_DIM * 8, p8);
        triplet_gather<<<EE / 4, 256, 0, stream>>>(p8, We_sbf2 + l * 8 * INTD, bufC,
                                                   idx_kj, offsT, tlist, bufD);
        // up-projection bufD -> buf2 (p8 dead now)
        gemm_k<64><<<EE / 32, 256, 0, stream>>>(bufD, nullptr, We_up + (size_t)l * INTD * HH,
                                                nullptr, nullptr, buf2, HH, 1);
        // e = silu((x_ji + x_kj) @ We_cat) -> catbuf (bufC..bufD dead)
        gemm_k<128><<<EE / 32, 256, 0, stream>>>(buf1, buf2, We_cat + (size_t)l * HH * HH,
                                                 nullptr, nullptr, catbuf, HH, 1);
        // residual before skip (NBS=1)
        gemm_k<128><<<EE / 32, 256, 0, stream>>>(catbuf, nullptr, Wres_b + (size_t)(l * 2 + 0) * HH * HH,
                                                 bres_b + (l * 2 + 0) * HH, nullptr, buf2, HH, 1);
        gemm_k<128><<<EE / 32, 256, 0, stream>>>(buf2, nullptr, Wres_b + (size_t)(l * 2 + 1) * HH * HH,
                                                 bres_b + (l * 2 + 1) * HH, catbuf, buf1, HH, 1);
        // e = silu(e @ We_lin + b) + e1
        gemm_k<128><<<EE / 32, 256, 0, stream>>>(buf1, nullptr, We_lin + (size_t)l * HH * HH,
                                                 be_lin + l * HH, e1, e1, HH, 1);
        // residual after skip (NAS=2)
        for (int r = 0; r < 2; ++r) {
            gemm_k<128><<<EE / 32, 256, 0, stream>>>(
                e1, nullptr, Wres_a + (size_t)((l * 2 + r) * 2 + 0) * HH * HH,
                bres_a + ((l * 2 + r) * 2 + 0) * HH, nullptr, buf2, HH, 1);
            gemm_k<128><<<EE / 32, 256, 0, stream>>>(
                buf2, nullptr, Wres_a + (size_t)((l * 2 + r) * 2 + 1) * HH * HH,
                bres_a + ((l * 2 + r) * 2 + 1) * HH, e1, e1, HH, 1);
        }
        // e2 -> node gather (no atomics, no memset) — uses We_rbf (NOT Crbf!)
        e2_gather<<<(NN + 1) / 2, 256, 0, stream>>>(rbf, We_rbf + (size_t)l * NRAD * HH,
                                                    e1, offsE, elist, vseg);
        // vn pipeline
        gemm_k<128><<<NN / 32, 256, 0, stream>>>(vseg, nullptr, Wv_up + (size_t)l * HH * OUT_EMB,
                                                 bv_up + l * OUT_EMB, nullptr, vn1, OUT_EMB, 0);
        gemm_k<256><<<NN / 32, 256, 0, stream>>>(vn1, nullptr, Wv_lins + (size_t)(l * 3 + 0) * 65536,
                                                 bv_lins + (l * 3 + 0) * 256, nullptr, vn2, OUT_EMB, 1);
        gemm_k<256><<<NN / 32, 256, 0, stream>>>(vn2, nullptr, Wv_lins + (size_t)(l * 3 + 1) * 65536,
                                                 bv_lins + (l * 3 + 1) * 256, nullptr, vn1, OUT_EMB, 1);
        gemm_k<256><<<NN / 32, 256, 0, stream>>>(vn1, nullptr, Wv_lins + (size_t)(l * 3 + 2) * 65536,
                                                 bv_lins + (l * 3 + 2) * 256, nullptr, vn2, OUT_EMB, 1);
        vout_scatter<<<NN / 4, 256, 0, stream>>>(vn2, Wv_out + l * OUT_EMB, batch, sbatch);
    }
    final_out<<<BB * HH / 256, 256, 0, stream>>>(u0, sbatch, out);
}

// Round 6
// 10606.844 us; speedup vs baseline: 3.6761x; 1.8598x over previous
//
#include <hip/hip_runtime.h>
#include <hip/hip_bf16.h>
#include <cstddef>

#define NN 20000
#define EE 400000
#define TT 1500000
#define BB 128
#define HH 128
#define INTD 64
#define OUT_EMB 256
#define SBF_DIM 42
#define NRAD 6

typedef __attribute__((ext_vector_type(8))) short bf16x8;
typedef __attribute__((ext_vector_type(4))) float f32x4;

__device__ __forceinline__ float silu_f(float v) {
    return v / (1.0f + __expf(-v));
}
__device__ __forceinline__ unsigned short f2b(float f) {
    __hip_bfloat16 h = __float2bfloat16(f);
    unsigned short u; __builtin_memcpy(&u, &h, 2); return u;
}
__device__ __forceinline__ float b2f(unsigned short u) {
    __hip_bfloat16 h; __builtin_memcpy(&h, &u, 2); return __bfloat162float(h);
}

// ---------------------------------------------------------------------------
// bf16 MFMA GEMM: out = [silu](A (+A2) @ W + bias) [+ res]; A bf16 [M,KK],
// Wt bf16 [NT][KK] (pre-transposed), out bf16 [M,NT] (+ optional fp32 outf).
// M-tile 128/block (grid = M/128), 256 threads = 4 waves.
// NT=128: wave -> 64x64 quadrant; NT=64: wave -> 32x64.
// ---------------------------------------------------------------------------
template <int KK, int NT>
__launch_bounds__(256)
__global__ void mfma_gemm(const unsigned short* __restrict__ A,
                          const unsigned short* __restrict__ A2,
                          const unsigned short* __restrict__ Wt,
                          const float* __restrict__ bias,
                          const float* __restrict__ resf,
                          const unsigned short* __restrict__ resb,
                          unsigned short* __restrict__ out,
                          float* __restrict__ outf, int act) {
    constexpr int SA = 88;   // LDS row stride (ushorts); 176B, dword-stride 44 mod 32 = 12
    __shared__ unsigned short As[128 * SA];
    __shared__ unsigned short Bs[NT * SA];

    const int tid = threadIdx.x;
    const size_t row0 = (size_t)blockIdx.x * 128;
    const int lane = tid & 63, wave = tid >> 6;
    const int lm = lane & 15, quad = lane >> 4;
    constexpr int MT = (NT == 128) ? 4 : 2;
    const int rw0 = (NT == 128) ? (wave >> 1) * 64 : wave * 32;
    const int cw0 = (NT == 128) ? (wave & 1) * 64 : 0;

    f32x4 acc[MT][4];
#pragma unroll
    for (int mi = 0; mi < MT; ++mi)
#pragma unroll
        for (int ni = 0; ni < 4; ++ni) acc[mi][ni] = (f32x4){0.f, 0.f, 0.f, 0.f};

    for (int kb = 0; kb < KK / 64; ++kb) {
        if (kb) __syncthreads();
        // stage A chunk (128 x 64 bf16), coalesced 16B
        for (int i = tid; i < 128 * 8; i += 256) {
            int r = i >> 3, seg = i & 7;
            uint4 va = *(const uint4*)(A + (row0 + r) * KK + kb * 64 + seg * 8);
            if (A2) {
                uint4 vb = *(const uint4*)(A2 + (row0 + r) * KK + kb * 64 + seg * 8);
                unsigned short* sa = (unsigned short*)&va;
                const unsigned short* sb = (const unsigned short*)&vb;
#pragma unroll
                for (int j = 0; j < 8; ++j) sa[j] = f2b(b2f(sa[j]) + b2f(sb[j]));
            }
            *(uint4*)&As[r * SA + seg * 8] = va;
        }
        // stage Wt chunk (NT x 64 bf16), coalesced 16B
        for (int i = tid; i < NT * 8; i += 256) {
            int n = i >> 3, seg = i & 7;
            *(uint4*)&Bs[n * SA + seg * 8] =
                *(const uint4*)(Wt + (size_t)n * KK + kb * 64 + seg * 8);
        }
        __syncthreads();
#pragma unroll
        for (int kc = 0; kc < 2; ++kc) {
            bf16x8 af[MT], bfv[4];
#pragma unroll
            for (int mi = 0; mi < MT; ++mi)
                af[mi] = *(const bf16x8*)&As[(rw0 + mi * 16 + lm) * SA + kc * 32 + quad * 8];
#pragma unroll
            for (int ni = 0; ni < 4; ++ni)
                bfv[ni] = *(const bf16x8*)&Bs[(cw0 + ni * 16 + lm) * SA + kc * 32 + quad * 8];
#pragma unroll
            for (int mi = 0; mi < MT; ++mi)
#pragma unroll
                for (int ni = 0; ni < 4; ++ni)
                    acc[mi][ni] = __builtin_amdgcn_mfma_f32_16x16x32_bf16(
                        af[mi], bfv[ni], acc[mi][ni], 0, 0, 0);
        }
    }
    // epilogue
#pragma unroll
    for (int mi = 0; mi < MT; ++mi)
#pragma unroll
        for (int ni = 0; ni < 4; ++ni) {
            int col = cw0 + ni * 16 + lm;
            float bv = bias ? bias[col] : 0.f;
#pragma unroll
            for (int r = 0; r < 4; ++r) {
                int row = rw0 + mi * 16 + quad * 4 + r;
                size_t off = (row0 + row) * (size_t)NT + col;
                float v = acc[mi][ni][r] + bv;
                if (act) v = silu_f(v);
                if (resf) v += resf[off];
                else if (resb) v += b2f(resb[off]);
                if (outf) outf[off] = v;
                out[off] = f2b(v);
            }
        }
}

// weight transpose+bf16: src fp32 [B,K,N] -> dst bf16 [B,N,K]
__global__ void transpose_w(const float* __restrict__ src, unsigned short* __restrict__ dst,
                            int B, int K, int N) {
    size_t total = (size_t)B * K * N;
    size_t i = (size_t)blockIdx.x * 256 + threadIdx.x;
    if (i >= total) return;
    int b = i / ((size_t)K * N);
    size_t rem = i - (size_t)b * K * N;
    int k = rem / N, n = rem % N;
    dst[(size_t)b * K * N + (size_t)n * K + k] = f2b(src[i]);
}

// ---------------------------------------------------------------------------
// fp32 GEMM (node pipeline + input projections), optional bf16 output copy
// ---------------------------------------------------------------------------
template <int K>
__launch_bounds__(256)
__global__ void gemm_k(const float* __restrict__ A, const float* __restrict__ W,
                       const float* __restrict__ bias, float* __restrict__ out,
                       unsigned short* __restrict__ outb, int N, int act) {
    constexpr int KC = (K <= 128) ? K : 128;
    __shared__ float As[32][KC + 1];
    __shared__ float Ws[KC * 64];
    const int tid = threadIdx.x;
    const size_t row0 = (size_t)blockIdx.x * 32;
    const int tx = tid & 15, ty = tid >> 4;
    const int c0 = tx * 4, r0 = ty * 2;

    for (int nc0 = 0; nc0 < N; nc0 += 64) {
        float acc[2][4] = {{0.f, 0.f, 0.f, 0.f}, {0.f, 0.f, 0.f, 0.f}};
        for (int kc0 = 0; kc0 < K; kc0 += KC) {
            __syncthreads();
            for (int idx = tid; idx < 32 * KC / 4; idx += 256) {
                int r = idx / (KC / 4);
                int kk = (idx % (KC / 4)) * 4;
                float4 v = *(const float4*)(A + (row0 + r) * K + kc0 + kk);
                As[r][kk] = v.x; As[r][kk + 1] = v.y;
                As[r][kk + 2] = v.z; As[r][kk + 3] = v.w;
            }
            for (int idx = tid; idx < KC * 16; idx += 256) {
                int k = idx >> 4;
                int cc = (idx & 15) * 4;
                *(float4*)&Ws[k * 64 + cc] =
                    *(const float4*)(W + (size_t)(kc0 + k) * N + nc0 + cc);
            }
            __syncthreads();
#pragma unroll 4
            for (int k = 0; k < KC; ++k) {
                float a0 = As[r0][k], a1 = As[r0 + 1][k];
                float4 w = *(const float4*)&Ws[k * 64 + c0];
                acc[0][0] += a0 * w.x; acc[0][1] += a0 * w.y;
                acc[0][2] += a0 * w.z; acc[0][3] += a0 * w.w;
                acc[1][0] += a1 * w.x; acc[1][1] += a1 * w.y;
                acc[1][2] += a1 * w.z; acc[1][3] += a1 * w.w;
            }
        }
#pragma unroll
        for (int i = 0; i < 2; ++i) {
            size_t off = (row0 + r0 + i) * N + nc0 + c0;
            float4 v = make_float4(acc[i][0], acc[i][1], acc[i][2], acc[i][3]);
            if (bias) {
                float4 b = *(const float4*)(bias + nc0 + c0);
                v.x += b.x; v.y += b.y; v.z += b.z; v.w += b.w;
            }
            if (act) {
                v.x = silu_f(v.x); v.y = silu_f(v.y);
                v.z = silu_f(v.z); v.w = silu_f(v.w);
            }
            if (out) *(float4*)(out + off) = v;
            if (outb) {
                ushort4 u = make_ushort4(f2b(v.x), f2b(v.y), f2b(v.z), f2b(v.w));
                *(ushort4*)(outb + off) = u;
            }
        }
    }
}

// C_rbf12[l] = We_rbf1[l] (6x8) @ We_rbf2[l] (8x128) -> [6,128]
__global__ void combine_rbf(const float* __restrict__ W1, const float* __restrict__ W2,
                            float* __restrict__ C) {
    int l = blockIdx.x;
    const float* w1 = W1 + l * 48;
    const float* w2 = W2 + l * 1024;
    float* c = C + l * 768;
    for (int idx = threadIdx.x; idx < 768; idx += 256) {
        int j = idx >> 7, h = idx & 127;
        float s = 0.f;
#pragma unroll
        for (int p = 0; p < 8; ++p) s += w1[j * 8 + p] * w2[p * 128 + h];
        c[idx] = s;
    }
}

// buf[e][h] *= rbf[e] @ C  (bf16 buffer)
__global__ void mul_rb(const float* __restrict__ rbf, const float* __restrict__ C,
                       unsigned short* __restrict__ buf) {
    int idx = blockIdx.x * 256 + threadIdx.x;   // over E*128
    int h = idx & 127;
    int e = idx >> 7;
    const float* rr = rbf + (size_t)e * NRAD;
    float r = 0.f;
#pragma unroll
    for (int j = 0; j < NRAD; ++j) r += rr[j] * C[j * 128 + h];
    buf[idx] = f2b(b2f(buf[idx]) * r);
}

// ------------------------- CSR build (multi-block scan) ----------------------
__global__ void hist_kernel(const int* __restrict__ idx, int n, int* __restrict__ cnt) {
    int t = blockIdx.x * 256 + threadIdx.x;
    if (t < n) atomicAdd(&cnt[idx[t]], 1);
}

__launch_bounds__(1024)
__global__ void scan1(const int* __restrict__ cnt, int n, int* __restrict__ offs,
                      int* __restrict__ partials) {
    __shared__ int tmp[1024];
    int tid = threadIdx.x;
    int i = blockIdx.x * 1024 + tid;
    int v = (i < n) ? cnt[i] : 0;
    tmp[tid] = v; __syncthreads();
    for (int d = 1; d < 1024; d <<= 1) {
        int t = (tid >= d) ? tmp[tid - d] : 0; __syncthreads();
        tmp[tid] += t; __syncthreads();
    }
    if (i < n) offs[i] = tmp[tid] - v;
    if (tid == 1023) partials[blockIdx.x] = tmp[1023];
}

__launch_bounds__(1024)
__global__ void scan2(int* __restrict__ partials, int nb, int n, int* __restrict__ offs) {
    __shared__ int tmp[1024];
    int tid = threadIdx.x;
    int v = (tid < nb) ? partials[tid] : 0;
    tmp[tid] = v; __syncthreads();
    for (int d = 1; d < 1024; d <<= 1) {
        int t = (tid >= d) ? tmp[tid - d] : 0; __syncthreads();
        tmp[tid] += t; __syncthreads();
    }
    if (tid < nb) partials[tid] = tmp[tid] - v;
    if (tid == 1023) offs[n] = tmp[1023];
}

__launch_bounds__(1024)
__global__ void scan3(int n, int* __restrict__ offs, const int* __restrict__ partials,
                      int* __restrict__ cur) {
    int i = blockIdx.x * 1024 + threadIdx.x;
    if (i < n) { int o = offs[i] + partials[blockIdx.x]; offs[i] = o; cur[i] = o; }
}

__global__ void fill_kernel(const int* __restrict__ idx, int n,
                            int* __restrict__ cur, int* __restrict__ lst) {
    int t = blockIdx.x * 256 + threadIdx.x;
    if (t < n) {
        int p = atomicAdd(&cur[idx[t]], 1);
        lst[p] = t;
    }
}

// ------------------------ triplet stage (gather form) ------------------------
__launch_bounds__(128)
__global__ void p8_kernel(const float* __restrict__ sbf, const float* __restrict__ W1,
                          float* __restrict__ p8) {
    __shared__ float S[128 * 43];
    __shared__ float Wl[SBF_DIM * 8];
    int tid = threadIdx.x;
    for (int i = tid; i < SBF_DIM * 8; i += 128) Wl[i] = W1[i];
    size_t base = (size_t)blockIdx.x * 128;
    int rows = (TT - base) < 128 ? (int)(TT - base) : 128;
    const float* src = sbf + base * SBF_DIM;
    for (int i = tid; i < rows * SBF_DIM; i += 128) {
        int r = i / SBF_DIM, j = i - r * SBF_DIM;
        S[r * 43 + j] = src[i];
    }
    __syncthreads();
    if (tid >= rows) return;
    float pv[8] = {0.f, 0.f, 0.f, 0.f, 0.f, 0.f, 0.f, 0.f};
    for (int j = 0; j < SBF_DIM; ++j) {
        float sv = S[tid * 43 + j];
#pragma unroll
        for (int p = 0; p < 8; ++p) pv[p] += sv * Wl[j * 8 + p];
    }
    float4* o = (float4*)(p8 + (base + tid) * 8);
    o[0] = make_float4(pv[0], pv[1], pv[2], pv[3]);
    o[1] = make_float4(pv[4], pv[5], pv[6], pv[7]);
}

// one wave per edge; xkj/agg bf16
__launch_bounds__(256)
__global__ void triplet_gather(const float* __restrict__ p8, const float* __restrict__ W2,
                               const unsigned short* __restrict__ xkj,
                               const int* __restrict__ idx_kj,
                               const int* __restrict__ offsT, const int* __restrict__ tlist,
                               unsigned short* __restrict__ agg) {
    int lane = threadIdx.x & 63;
    int wv = threadIdx.x >> 6;
    int e = blockIdx.x * 4 + wv;
    if (e >= EE) return;
    float w2c[8];
#pragma unroll
    for (int p = 0; p < 8; ++p) w2c[p] = W2[p * INTD + lane];
    int b = offsT[e], en = offsT[e + 1];
    float acc = 0.f;
    for (int q = b; q < en; ++q) {
        int t = tlist[q];
        int k = idx_kj[t];
        const float4* pr = (const float4*)(p8 + (size_t)t * 8);
        float4 p0 = pr[0], p1 = pr[1];
        float s = p0.x * w2c[0] + p0.y * w2c[1] + p0.z * w2c[2] + p0.w * w2c[3]
                + p1.x * w2c[4] + p1.y * w2c[5] + p1.z * w2c[6] + p1.w * w2c[7];
        acc += s * b2f(xkj[(size_t)k * INTD + lane]);
    }
    agg[(size_t)e * INTD + lane] = f2b(acc);
}

// vseg[n][h] = sum_e (rbf[e]@Wr)[h] * e1f[e][h]   (fp32 e1 master)
__launch_bounds__(256)
__global__ void e2_gather(const float* __restrict__ rbf, const float* __restrict__ Wr,
                          const float* __restrict__ e1f, const int* __restrict__ offsE,
                          const int* __restrict__ elist, float* __restrict__ vseg) {
    int h = threadIdx.x & 127;
    int sub = threadIdx.x >> 7;
    int n = blockIdx.x * 2 + sub;
    if (n >= NN) return;
    float c0 = Wr[0 * 128 + h], c1 = Wr[1 * 128 + h], c2 = Wr[2 * 128 + h],
          c3 = Wr[3 * 128 + h], c4 = Wr[4 * 128 + h], c5 = Wr[5 * 128 + h];
    int b = offsE[n], en = offsE[n + 1];
    float acc = 0.f;
    for (int q = b; q < en; ++q) {
        int e = elist[q];
        const float* rr = rbf + (size_t)e * NRAD;
        float r = rr[0] * c0 + rr[1] * c1 + rr[2] * c2 + rr[3] * c3 + rr[4] * c4 + rr[5] * c5;
        acc += r * e1f[(size_t)e * 128 + h];
    }
    vseg[(size_t)n * 128 + h] = acc;
}

__global__ void scatter_u0(const float* __restrict__ v, const int* __restrict__ batch,
                           float* __restrict__ u0) {
    int idx = blockIdx.x * 256 + threadIdx.x;
    int h = idx & 127;
    int n = idx >> 7;
    atomicAdd(&u0[(size_t)batch[n] * 128 + h], v[idx]);
}

__launch_bounds__(256)
__global__ void vout_scatter(const float* __restrict__ vn, const float* __restrict__ Wv_out,
                             const int* __restrict__ batch, float* __restrict__ sbatch) {
    int wave = threadIdx.x >> 6, lane = threadIdx.x & 63;
    int n = blockIdx.x * 4 + wave;
    if (n >= NN) return;
    const float* row = vn + (size_t)n * OUT_EMB;
    float s = 0.f;
#pragma unroll
    for (int k = lane; k < OUT_EMB; k += 64) s += row[k] * Wv_out[k];
#pragma unroll
    for (int off = 32; off > 0; off >>= 1) s += __shfl_down(s, off);
    if (lane == 0) atomicAdd(&sbatch[batch[n]], s);
}

__global__ void final_out(const float* __restrict__ u0, const float* __restrict__ sb,
                          float* __restrict__ out) {
    int idx = blockIdx.x * 256 + threadIdx.x;
    out[idx] = u0[idx] + sb[idx >> 7];
}

extern "C" void kernel_launch(void* const* d_in, const int* in_sizes, int n_in,
                              void* d_out, int out_size, void* d_ws, size_t ws_size,
                              hipStream_t stream) {
    const float* x         = (const float*)d_in[0];
    const float* edge_attr = (const float*)d_in[1];
    const float* rbf       = (const float*)d_in[2];
    const float* sbf       = (const float*)d_in[3];
    const int*   iidx      = (const int*)d_in[4];
    const int*   idx_kj    = (const int*)d_in[5];
    const int*   idx_ji    = (const int*)d_in[6];
    const int*   batch     = (const int*)d_in[7];
    const float* W_node    = (const float*)d_in[8];
    const float* W_edge    = (const float*)d_in[9];
    const float* We_rbf1   = (const float*)d_in[10];
    const float* We_rbf2   = (const float*)d_in[11];
    const float* We_sbf1   = (const float*)d_in[12];
    const float* We_sbf2   = (const float*)d_in[13];
    const float* We_rbf    = (const float*)d_in[14];
    const float* We_kj     = (const float*)d_in[15];
    const float* be_kj     = (const float*)d_in[16];
    const float* We_ji     = (const float*)d_in[17];
    const float* be_ji     = (const float*)d_in[18];
    const float* We_down   = (const float*)d_in[19];
    const float* We_up     = (const float*)d_in[20];
    const float* We_cat    = (const float*)d_in[21];
    const float* Wres_b    = (const float*)d_in[22];
    const float* bres_b    = (const float*)d_in[23];
    const float* We_lin    = (const float*)d_in[24];
    const float* be_lin    = (const float*)d_in[25];
    const float* Wres_a    = (const float*)d_in[26];
    const float* bres_a    = (const float*)d_in[27];
    const float* Wv_up     = (const float*)d_in[28];
    const float* bv_up     = (const float*)d_in[29];
    const float* Wv_lins   = (const float*)d_in[30];
    const float* bv_lins   = (const float*)d_in[31];
    const float* Wv_out    = (const float*)d_in[32];
    float* out = (float*)d_out;

    // ---- workspace layout ----
    unsigned short* e1b  = (unsigned short*)d_ws;            // E*128 bf16
    unsigned short* buf1 = e1b  + (size_t)EE * HH;           // E*128 bf16
    unsigned short* buf2 = buf1 + (size_t)EE * HH;           // E*128 bf16 (alias p8 fp32)
    unsigned short* bufC = buf2 + (size_t)EE * HH;           // E*64 bf16 (xkj_down)
    unsigned short* bufD = bufC + (size_t)EE * INTD;         // E*64 bf16 (agg)
    unsigned short* endu = bufD + (size_t)EE * INTD;
    float* e1f    = (float*)endu;                            // E*128 fp32 master
    float* tail   = e1f + (size_t)EE * HH;
    float* u0     = tail;                                    // B*128
    float* sbatch = u0 + BB * HH;                            // 256
    float* Crbf   = sbatch + 256;                            // 4*768
    int*   iptr   = (int*)(Crbf + 4 * 768);
    int* cntT  = iptr;               iptr += EE;
    int* offsT = iptr;               iptr += EE + 1;
    int* curT  = iptr;               iptr += EE;
    int* tlist = iptr;               iptr += TT;
    int* cntE  = iptr;               iptr += NN;
    int* offsE = iptr;               iptr += NN + 1;
    int* curE  = iptr;               iptr += NN;
    int* elist = iptr;               iptr += EE;
    int* partials = iptr;            iptr += 1024;
    // transposed bf16 weights
    unsigned short* wptr = (unsigned short*)iptr;
    unsigned short* wt_ji   = wptr;  wptr += 4 * 16384;
    unsigned short* wt_kj   = wptr;  wptr += 4 * 16384;
    unsigned short* wt_down = wptr;  wptr += 4 * 8192;
    unsigned short* wt_up   = wptr;  wptr += 4 * 8192;
    unsigned short* wt_cat  = wptr;  wptr += 4 * 16384;
    unsigned short* wt_resb = wptr;  wptr += 8 * 16384;
    unsigned short* wt_lin  = wptr;  wptr += 4 * 16384;
    unsigned short* wt_resa = wptr;  wptr += 16 * 16384;
    // aliases
    float* p8 = (float*)buf2;                                // [T,8] fp32 (48MB < 102MB)
    unsigned short* catbuf = bufC;                           // E*128 bf16 over bufC..bufD
    float* vseg = (float*)bufC;                              // N*128 fp32
    float* vn1  = vseg + (size_t)NN * HH;                    // N*256
    float* vn2  = vn1 + (size_t)NN * OUT_EMB;                // N*256

    hipMemsetAsync(u0, 0, (size_t)BB * HH * sizeof(float), stream);
    hipMemsetAsync(sbatch, 0, 256 * sizeof(float), stream);
    combine_rbf<<<4, 256, 0, stream>>>(We_rbf1, We_rbf2, Crbf);

    // ---- weight transpose + bf16 convert (tiny) ----
    transpose_w<<<(4 * 16384 + 255) / 256, 256, 0, stream>>>(We_ji, wt_ji, 4, 128, 128);
    transpose_w<<<(4 * 16384 + 255) / 256, 256, 0, stream>>>(We_kj, wt_kj, 4, 128, 128);
    transpose_w<<<(4 * 8192 + 255) / 256, 256, 0, stream>>>(We_down, wt_down, 4, 128, 64);
    transpose_w<<<(4 * 8192 + 255) / 256, 256, 0, stream>>>(We_up, wt_up, 4, 64, 128);
    transpose_w<<<(4 * 16384 + 255) / 256, 256, 0, stream>>>(We_cat, wt_cat, 4, 128, 128);
    transpose_w<<<(8 * 16384 + 255) / 256, 256, 0, stream>>>(Wres_b, wt_resb, 8, 128, 128);
    transpose_w<<<(4 * 16384 + 255) / 256, 256, 0, stream>>>(We_lin, wt_lin, 4, 128, 128);
    transpose_w<<<(16 * 16384 + 255) / 256, 256, 0, stream>>>(Wres_a, wt_resa, 16, 128, 128);

    // ---- CSR builds ----
    hipMemsetAsync(cntT, 0, EE * sizeof(int), stream);
    hipMemsetAsync(cntE, 0, NN * sizeof(int), stream);
    hist_kernel<<<(TT + 255) / 256, 256, 0, stream>>>(idx_ji, TT, cntT);
    hist_kernel<<<(EE + 255) / 256, 256, 0, stream>>>(iidx, EE, cntE);
    int nbT = (EE + 1023) / 1024, nbE = (NN + 1023) / 1024;
    scan1<<<nbT, 1024, 0, stream>>>(cntT, EE, offsT, partials);
    scan2<<<1, 1024, 0, stream>>>(partials, nbT, EE, offsT);
    scan3<<<nbT, 1024, 0, stream>>>(EE, offsT, partials, curT);
    fill_kernel<<<(TT + 255) / 256, 256, 0, stream>>>(idx_ji, TT, curT, tlist);
    scan1<<<nbE, 1024, 0, stream>>>(cntE, NN, offsE, partials);
    scan2<<<1, 1024, 0, stream>>>(partials, nbE, NN, offsE);
    scan3<<<nbE, 1024, 0, stream>>>(NN, offsE, partials, curE);
    fill_kernel<<<(EE + 255) / 256, 256, 0, stream>>>(iidx, EE, curE, elist);

    // e1 = edge_attr @ W_edge (fp32 master + bf16 shadow)
    gemm_k<12><<<EE / 32, 256, 0, stream>>>(edge_attr, W_edge, nullptr, e1f, e1b, HH, 0);
    // v = x @ W_node -> vseg; u0 = seg(v, batch)
    gemm_k<48><<<NN / 32, 256, 0, stream>>>(x, W_node, nullptr, vseg, nullptr, HH, 0);
    scatter_u0<<<NN * HH / 256, 256, 0, stream>>>(vseg, batch, u0);

    const int GR = EE / 128;  // 3125
    for (int l = 0; l < 4; ++l) {
        // x_ji, x_kj
        mfma_gemm<128, 128><<<GR, 256, 0, stream>>>(e1b, nullptr, wt_ji + l * 16384,
            be_ji + l * HH, nullptr, nullptr, buf1, nullptr, 1);
        mfma_gemm<128, 128><<<GR, 256, 0, stream>>>(e1b, nullptr, wt_kj + l * 16384,
            be_kj + l * HH, nullptr, nullptr, buf2, nullptr, 1);
        mul_rb<<<EE * HH / 256, 256, 0, stream>>>(rbf, Crbf + l * 768, buf2);
        // down-projection buf2 -> bufC
        mfma_gemm<128, 64><<<GR, 256, 0, stream>>>(buf2, nullptr, wt_down + l * 8192,
            nullptr, nullptr, nullptr, bufC, nullptr, 1);
        // triplet stage
        p8_kernel<<<(TT + 127) / 128, 128, 0, stream>>>(sbf, We_sbf1 + l * SBF_DIM * 8, p8);
        triplet_gather<<<EE / 4, 256, 0, stream>>>(p8, We_sbf2 + l * 8 * INTD, bufC,
                                                   idx_kj, offsT, tlist, bufD);
        // up-projection bufD -> buf2 (p8 dead)
        mfma_gemm<64, 128><<<GR, 256, 0, stream>>>(bufD, nullptr, wt_up + l * 8192,
            nullptr, nullptr, nullptr, buf2, nullptr, 1);
        // cat: silu((x_ji + x_kj) @ We_cat) -> catbuf
        mfma_gemm<128, 128><<<GR, 256, 0, stream>>>(buf1, buf2, wt_cat + l * 16384,
            nullptr, nullptr, nullptr, catbuf, nullptr, 1);
        // residual before skip
        mfma_gemm<128, 128><<<GR, 256, 0, stream>>>(catbuf, nullptr, wt_resb + (l * 2 + 0) * 16384,
            bres_b + (l * 2 + 0) * HH, nullptr, nullptr, buf2, nullptr, 1);
        mfma_gemm<128, 128><<<GR, 256, 0, stream>>>(buf2, nullptr, wt_resb + (l * 2 + 1) * 16384,
            bres_b + (l * 2 + 1) * HH, nullptr, catbuf, buf1, nullptr, 1);
        // e = silu(e @ We_lin + b) + e1   (fp32 master path)
        mfma_gemm<128, 128><<<GR, 256, 0, stream>>>(buf1, nullptr, wt_lin + l * 16384,
            be_lin + l * HH, e1f, nullptr, e1b, e1f, 1);
        // residual after skip (NAS=2)
        for (int r = 0; r < 2; ++r) {
            mfma_gemm<128, 128><<<GR, 256, 0, stream>>>(e1b, nullptr,
                wt_resa + ((l * 2 + r) * 2 + 0) * 16384,
                bres_a + ((l * 2 + r) * 2 + 0) * HH, nullptr, nullptr, buf2, nullptr, 1);
            mfma_gemm<128, 128><<<GR, 256, 0, stream>>>(buf2, nullptr,
                wt_resa + ((l * 2 + r) * 2 + 1) * 16384,
                bres_a + ((l * 2 + r) * 2 + 1) * HH, e1f, nullptr, e1b, e1f, 1);
        }
        // e2 -> node gather (fp32 e1 master)
        e2_gather<<<(NN + 1) / 2, 256, 0, stream>>>(rbf, We_rbf + (size_t)l * NRAD * HH,
                                                    e1f, offsE, elist, vseg);
        // node pipeline (fp32)
        gemm_k<128><<<NN / 32, 256, 0, stream>>>(vseg, Wv_up + (size_t)l * HH * OUT_EMB,
                                                 bv_up + l * OUT_EMB, vn1, nullptr, OUT_EMB, 0);
        gemm_k<256><<<NN / 32, 256, 0, stream>>>(vn1, Wv_lins + (size_t)(l * 3 + 0) * 65536,
                                                 bv_lins + (l * 3 + 0) * 256, vn2, nullptr, OUT_EMB, 1);
        gemm_k<256><<<NN / 32, 256, 0, stream>>>(vn2, Wv_lins + (size_t)(l * 3 + 1) * 65536,
                                                 bv_lins + (l * 3 + 1) * 256, vn1, nullptr, OUT_EMB, 1);
        gemm_k<256><<<NN / 32, 256, 0, stream>>>(vn1, Wv_lins + (size_t)(l * 3 + 2) * 65536,
                                                 bv_lins + (l * 3 + 2) * 256, vn2, nullptr, OUT_EMB, 1);
        vout_scatter<<<NN / 4, 256, 0, stream>>>(vn2, Wv_out + l * OUT_EMB, batch, sbatch);
    }
    final_out<<<BB * HH / 256, 256, 0, stream>>>(u0, sbatch, out);
}

// Round 7
// 8177.493 us; speedup vs baseline: 4.7682x; 1.2971x over previous
//
#include <hip/hip_runtime.h>
#include <hip/hip_bf16.h>
#include <cstddef>

#define NN 20000
#define EE 400000
#define TT 1500000
#define BB 128
#define HH 128
#define INTD 64
#define OUT_EMB 256
#define SBF_DIM 42
#define NRAD 6

#define SA_C 136   // Cs row stride (ushorts): 272B, 16B-aligned, 2-way bank (free)
#define SA_B 72    // Bs row stride (ushorts): 144B, 16B-aligned, 2-way bank (free)

typedef __attribute__((ext_vector_type(8))) short bf16x8;
typedef __attribute__((ext_vector_type(4))) float f32x4;

__device__ __forceinline__ float silu_f(float v) {
    return v / (1.0f + __expf(-v));
}
__device__ __forceinline__ unsigned short f2b(float f) {
    __hip_bfloat16 h = __float2bfloat16(f);
    unsigned short u; __builtin_memcpy(&u, &h, 2); return u;
}
__device__ __forceinline__ float b2f(unsigned short u) {
    __hip_bfloat16 h; __builtin_memcpy(&h, &u, 2); return __bfloat162float(h);
}

__device__ __forceinline__ void zero_acc(f32x4 a[4][4]) {
#pragma unroll
    for (int mi = 0; mi < 4; ++mi)
#pragma unroll
        for (int ni = 0; ni < 4; ++ni) a[mi][ni] = (f32x4){0.f, 0.f, 0.f, 0.f};
}

// stage W [128][128] cols [kofs,kofs+64) into Bs
__device__ __forceinline__ void stageB128(unsigned short* Bs, const unsigned short* W,
                                          int kofs, int tid) {
    for (int i = tid; i < 128 * 8; i += 256) {
        int n = i >> 3, seg = i & 7;
        *(uint4*)&Bs[n * SA_B + seg * 8] = *(const uint4*)(W + n * 128 + kofs + seg * 8);
    }
}
// stage W [128][64] (K=64) into Bs
__device__ __forceinline__ void stageB64K(unsigned short* Bs, const unsigned short* W, int tid) {
    for (int i = tid; i < 128 * 8; i += 256) {
        int n = i >> 3, seg = i & 7;
        *(uint4*)&Bs[n * SA_B + seg * 8] = *(const uint4*)(W + n * 64 + seg * 8);
    }
}
// stage W [64][128] cols [kofs,kofs+64) into Bs (down weights)
__device__ __forceinline__ void stageBdown(unsigned short* Bs, const unsigned short* W,
                                           int kofs, int tid) {
    for (int i = tid; i < 64 * 8; i += 256) {
        int n = i >> 3, seg = i & 7;
        *(uint4*)&Bs[n * SA_B + seg * 8] = *(const uint4*)(W + n * 128 + kofs + seg * 8);
    }
}

// 64x64 wave tile, K-chunk of 64 from Cs[.,kofs..kofs+64) x Bs[.,0..64)
__device__ __forceinline__ void mfma_chunk(const unsigned short* Cs, int kofs,
                                           const unsigned short* Bs, int lm, int quad,
                                           int rw0, int cw0, f32x4 acc[4][4]) {
#pragma unroll
    for (int kc = 0; kc < 2; ++kc) {
        bf16x8 af[4], bv[4];
#pragma unroll
        for (int mi = 0; mi < 4; ++mi)
            af[mi] = *(const bf16x8*)&Cs[(rw0 + mi * 16 + lm) * SA_C + kofs + kc * 32 + quad * 8];
#pragma unroll
        for (int ni = 0; ni < 4; ++ni)
            bv[ni] = *(const bf16x8*)&Bs[(cw0 + ni * 16 + lm) * SA_B + kc * 32 + quad * 8];
#pragma unroll
        for (int mi = 0; mi < 4; ++mi)
#pragma unroll
            for (int ni = 0; ni < 4; ++ni)
                acc[mi][ni] = __builtin_amdgcn_mfma_f32_16x16x32_bf16(af[mi], bv[ni], acc[mi][ni], 0, 0, 0);
    }
}

// 32x64 wave tile (N=64 down GEMM)
__device__ __forceinline__ void mfma_chunk_d(const unsigned short* Cs, int kofs,
                                             const unsigned short* Bs, int lm, int quad,
                                             int rw0d, f32x4 acc[2][4]) {
#pragma unroll
    for (int kc = 0; kc < 2; ++kc) {
        bf16x8 af[2], bv[4];
#pragma unroll
        for (int mi = 0; mi < 2; ++mi)
            af[mi] = *(const bf16x8*)&Cs[(rw0d + mi * 16 + lm) * SA_C + kofs + kc * 32 + quad * 8];
#pragma unroll
        for (int ni = 0; ni < 4; ++ni)
            bv[ni] = *(const bf16x8*)&Bs[(ni * 16 + lm) * SA_B + kc * 32 + quad * 8];
#pragma unroll
        for (int mi = 0; mi < 2; ++mi)
#pragma unroll
            for (int ni = 0; ni < 4; ++ni)
                acc[mi][ni] = __builtin_amdgcn_mfma_f32_16x16x32_bf16(af[mi], bv[ni], acc[mi][ni], 0, 0, 0);
    }
}

// ---------------------------------------------------------------------------
// MK1: x_ji = silu(e1@Wji+bji) -> buf1 ; x_kj = silu(e1@Wkj+bkj)*r ;
//      bufC = silu(x_kjr @ Wdown)          [one 128-row tile per block]
// ---------------------------------------------------------------------------
__global__ __launch_bounds__(256)
void mk1(const unsigned short* __restrict__ e1b,
         const unsigned short* __restrict__ w_ji, const unsigned short* __restrict__ w_kj,
         const unsigned short* __restrict__ w_down,
         const float* __restrict__ be_ji, const float* __restrict__ be_kj,
         const float* __restrict__ rbf, const float* __restrict__ Crbf_l,
         unsigned short* __restrict__ buf1, unsigned short* __restrict__ bufC) {
    __shared__ unsigned short Cs[128 * SA_C];
    __shared__ unsigned short Bs[128 * SA_B];
    __shared__ float rbfS[128 * 6];
    __shared__ float CrbfS[768];

    const int tid = threadIdx.x;
    const size_t row0 = (size_t)blockIdx.x * 128;
    const int lane = tid & 63, wave = tid >> 6, lm = lane & 15, quad = lane >> 4;
    const int rw0 = (wave >> 1) * 64, cw0 = (wave & 1) * 64;
    const int rw0d = wave * 32;

    // initial staging: Cs <- e1b tile (full K=128), Bs <- Wji kb0, rbf+Crbf tiles
    for (int i = tid; i < 128 * 16; i += 256) {
        int r = i >> 4, seg = i & 15;
        *(uint4*)&Cs[r * SA_C + seg * 8] = *(const uint4*)(e1b + (row0 + r) * 128 + seg * 8);
    }
    stageB128(Bs, w_ji, 0, tid);
    for (int i = tid; i < 768; i += 256) { rbfS[i] = rbf[row0 * 6 + i]; CrbfS[i] = Crbf_l[i]; }
    __syncthreads();

    // ji GEMM -> jreg (held in registers until the end)
    f32x4 jreg[4][4], acc[4][4];
    zero_acc(jreg);
    mfma_chunk(Cs, 0, Bs, lm, quad, rw0, cw0, jreg);
    __syncthreads();
    stageB128(Bs, w_ji, 64, tid);
    __syncthreads();
    mfma_chunk(Cs, 64, Bs, lm, quad, rw0, cw0, jreg);
    __syncthreads();
    stageB128(Bs, w_kj, 0, tid);
    __syncthreads();

    // kj GEMM
    zero_acc(acc);
    mfma_chunk(Cs, 0, Bs, lm, quad, rw0, cw0, acc);
    __syncthreads();
    stageB128(Bs, w_kj, 64, tid);
    __syncthreads();
    mfma_chunk(Cs, 64, Bs, lm, quad, rw0, cw0, acc);
    __syncthreads();
    // epi kj: silu + bias, then r-scale; overwrite Cs (e1b reads done); stage down kb0
#pragma unroll
    for (int mi = 0; mi < 4; ++mi)
#pragma unroll
        for (int r = 0; r < 4; ++r) {
            int row = rw0 + mi * 16 + quad * 4 + r;
            float rb[6];
#pragma unroll
            for (int j = 0; j < 6; ++j) rb[j] = rbfS[row * 6 + j];
#pragma unroll
            for (int ni = 0; ni < 4; ++ni) {
                int col = cw0 + ni * 16 + lm;
                float rv = rb[0] * CrbfS[col] + rb[1] * CrbfS[128 + col] + rb[2] * CrbfS[256 + col]
                         + rb[3] * CrbfS[384 + col] + rb[4] * CrbfS[512 + col] + rb[5] * CrbfS[640 + col];
                float v = silu_f(acc[mi][ni][r] + be_kj[col]);
                Cs[row * SA_C + col] = f2b(b2f(f2b(v)) * rv);
            }
        }
    stageBdown(Bs, w_down, 0, tid);
    __syncthreads();

    // down GEMM (N=64)
    f32x4 accd[2][4];
#pragma unroll
    for (int mi = 0; mi < 2; ++mi)
#pragma unroll
        for (int ni = 0; ni < 4; ++ni) accd[mi][ni] = (f32x4){0.f, 0.f, 0.f, 0.f};
    mfma_chunk_d(Cs, 0, Bs, lm, quad, rw0d, accd);
    __syncthreads();
    stageBdown(Bs, w_down, 64, tid);
    __syncthreads();
    mfma_chunk_d(Cs, 64, Bs, lm, quad, rw0d, accd);
    __syncthreads();
    // epi down -> Cs cols 0..63
#pragma unroll
    for (int mi = 0; mi < 2; ++mi)
#pragma unroll
        for (int ni = 0; ni < 4; ++ni) {
            int col = ni * 16 + lm;
#pragma unroll
            for (int r = 0; r < 4; ++r) {
                int row = rw0d + mi * 16 + quad * 4 + r;
                Cs[row * SA_C + col] = f2b(silu_f(accd[mi][ni][r]));
            }
        }
    __syncthreads();
    // coalesced copy Cs(128x64) -> bufC
    for (int i = tid; i < 128 * 8; i += 256) {
        int r = i >> 3, seg = i & 7;
        *(uint4*)(bufC + (row0 + r) * 64 + seg * 8) = *(const uint4*)&Cs[r * SA_C + seg * 8];
    }
    __syncthreads();
    // epi ji -> Cs, then coalesced copy -> buf1
#pragma unroll
    for (int mi = 0; mi < 4; ++mi)
#pragma unroll
        for (int ni = 0; ni < 4; ++ni) {
            int col = cw0 + ni * 16 + lm;
            float bb = be_ji[col];
#pragma unroll
            for (int r = 0; r < 4; ++r) {
                int row = rw0 + mi * 16 + quad * 4 + r;
                Cs[row * SA_C + col] = f2b(silu_f(jreg[mi][ni][r] + bb));
            }
        }
    __syncthreads();
    for (int i = tid; i < 128 * 16; i += 256) {
        int r = i >> 4, seg = i & 15;
        *(uint4*)(buf1 + (row0 + r) * 128 + seg * 8) = *(const uint4*)&Cs[r * SA_C + seg * 8];
    }
}

// ---------------------------------------------------------------------------
// MK2: up -> (+x_ji) cat -> rb0a -> rb0b(+state) -> lin(+e1f_old, state=) ->
//      ra0a -> ra0b(+state) -> ra1a -> ra1b(+state) -> write e1f, e1b
// ---------------------------------------------------------------------------
__global__ __launch_bounds__(256)
void mk2(const unsigned short* __restrict__ bufD, const unsigned short* __restrict__ buf1g,
         float* __restrict__ e1f, unsigned short* __restrict__ e1b,
         const unsigned short* __restrict__ w_up, const unsigned short* __restrict__ w_cat,
         const unsigned short* __restrict__ w_rb0, const unsigned short* __restrict__ w_rb1,
         const unsigned short* __restrict__ w_lin,
         const unsigned short* __restrict__ w_ra0, const unsigned short* __restrict__ w_ra1,
         const unsigned short* __restrict__ w_ra2, const unsigned short* __restrict__ w_ra3,
         const float* __restrict__ b_rb0, const float* __restrict__ b_rb1,
         const float* __restrict__ b_lin,
         const float* __restrict__ b_ra0, const float* __restrict__ b_ra1,
         const float* __restrict__ b_ra2, const float* __restrict__ b_ra3) {
    __shared__ unsigned short Cs[128 * SA_C];
    __shared__ unsigned short Bs[128 * SA_B];

    const int tid = threadIdx.x;
    const size_t row0 = (size_t)blockIdx.x * 128;
    const int lane = tid & 63, wave = tid >> 6, lm = lane & 15, quad = lane >> 4;
    const int rw0 = (wave >> 1) * 64, cw0 = (wave & 1) * 64;

    f32x4 acc[4][4], state[4][4];

#define K128_BODY(WSTAGE)                                  \
    zero_acc(acc);                                         \
    mfma_chunk(Cs, 0, Bs, lm, quad, rw0, cw0, acc);        \
    __syncthreads();                                       \
    stageB128(Bs, WSTAGE, 64, tid);                        \
    __syncthreads();                                       \
    mfma_chunk(Cs, 64, Bs, lm, quad, rw0, cw0, acc);       \
    __syncthreads();

#define FOR_TILE(body)                                          \
    _Pragma("unroll") for (int mi = 0; mi < 4; ++mi) {          \
    _Pragma("unroll") for (int ni = 0; ni < 4; ++ni) {          \
        int col = cw0 + ni * 16 + lm;                           \
    _Pragma("unroll") for (int r = 0; r < 4; ++r) {             \
        int row = rw0 + mi * 16 + quad * 4 + r; body } } }

    // initial staging: Cs <- bufD tile (K=64), Bs <- Wup (K=64 full)
    for (int i = tid; i < 128 * 8; i += 256) {
        int r = i >> 3, seg = i & 7;
        *(uint4*)&Cs[r * SA_C + seg * 8] = *(const uint4*)(bufD + (row0 + r) * 64 + seg * 8);
    }
    stageB64K(Bs, w_up, tid);
    __syncthreads();

    // ---- up (K=64, no bias) ----
    zero_acc(acc);
    mfma_chunk(Cs, 0, Bs, lm, quad, rw0, cw0, acc);
    __syncthreads();
    // epi: Cs = bf16(x_ji + bf16(silu(acc)))
    FOR_TILE({
        float v = silu_f(acc[mi][ni][r]);
        unsigned short xj = buf1g[(row0 + row) * 128 + col];
        Cs[row * SA_C + col] = f2b(b2f(xj) + b2f(f2b(v)));
    })
    stageB128(Bs, w_cat, 0, tid);
    __syncthreads();

    // ---- cat (no bias): state = silu(acc) ----
    K128_BODY(w_cat)
    FOR_TILE({
        float v = silu_f(acc[mi][ni][r]);
        state[mi][ni][r] = v;
        Cs[row * SA_C + col] = f2b(v);
    })
    stageB128(Bs, w_rb0, 0, tid);
    __syncthreads();

    // ---- rb0a ----
    K128_BODY(w_rb0)
    FOR_TILE({
        float v = silu_f(acc[mi][ni][r] + b_rb0[col]);
        Cs[row * SA_C + col] = f2b(v);
    })
    stageB128(Bs, w_rb1, 0, tid);
    __syncthreads();

    // ---- rb0b: state += silu ----
    K128_BODY(w_rb1)
    FOR_TILE({
        float v = state[mi][ni][r] + silu_f(acc[mi][ni][r] + b_rb1[col]);
        state[mi][ni][r] = v;
        Cs[row * SA_C + col] = f2b(v);
    })
    stageB128(Bs, w_lin, 0, tid);
    __syncthreads();

    // ---- lin: state = silu(acc+b) + e1f_old ----
    K128_BODY(w_lin)
    FOR_TILE({
        float v = silu_f(acc[mi][ni][r] + b_lin[col]) + e1f[(row0 + row) * 128 + col];
        state[mi][ni][r] = v;
        Cs[row * SA_C + col] = f2b(v);
    })
    stageB128(Bs, w_ra0, 0, tid);
    __syncthreads();

    // ---- ra0a ----
    K128_BODY(w_ra0)
    FOR_TILE({
        float v = silu_f(acc[mi][ni][r] + b_ra0[col]);
        Cs[row * SA_C + col] = f2b(v);
    })
    stageB128(Bs, w_ra1, 0, tid);
    __syncthreads();

    // ---- ra0b: state += silu ----
    K128_BODY(w_ra1)
    FOR_TILE({
        float v = state[mi][ni][r] + silu_f(acc[mi][ni][r] + b_ra1[col]);
        state[mi][ni][r] = v;
        Cs[row * SA_C + col] = f2b(v);
    })
    stageB128(Bs, w_ra2, 0, tid);
    __syncthreads();

    // ---- ra1a ----
    K128_BODY(w_ra2)
    FOR_TILE({
        float v = silu_f(acc[mi][ni][r] + b_ra2[col]);
        Cs[row * SA_C + col] = f2b(v);
    })
    stageB128(Bs, w_ra3, 0, tid);
    __syncthreads();

    // ---- ra1b: state += silu; writeback ----
    K128_BODY(w_ra3)
    FOR_TILE({
        float v = state[mi][ni][r] + silu_f(acc[mi][ni][r] + b_ra3[col]);
        state[mi][ni][r] = v;
        e1f[(row0 + row) * 128 + col] = v;
        Cs[row * SA_C + col] = f2b(v);
    })
    __syncthreads();
    for (int i = tid; i < 128 * 16; i += 256) {
        int r = i >> 4, seg = i & 15;
        *(uint4*)(e1b + (row0 + r) * 128 + seg * 8) = *(const uint4*)&Cs[r * SA_C + seg * 8];
    }
#undef K128_BODY
#undef FOR_TILE
}

// weight transpose+bf16: src fp32 [B,K,N] -> dst bf16 [B,N,K]
__global__ void transpose_w(const float* __restrict__ src, unsigned short* __restrict__ dst,
                            int B, int K, int N) {
    size_t total = (size_t)B * K * N;
    size_t i = (size_t)blockIdx.x * 256 + threadIdx.x;
    if (i >= total) return;
    int b = i / ((size_t)K * N);
    size_t rem = i - (size_t)b * K * N;
    int k = rem / N, n = rem % N;
    dst[(size_t)b * K * N + (size_t)n * K + k] = f2b(src[i]);
}

// ---------------------------------------------------------------------------
// fp32 GEMM (node pipeline + input projections), optional bf16 output copy
// ---------------------------------------------------------------------------
template <int K>
__launch_bounds__(256)
__global__ void gemm_k(const float* __restrict__ A, const float* __restrict__ W,
                       const float* __restrict__ bias, float* __restrict__ out,
                       unsigned short* __restrict__ outb, int N, int act) {
    constexpr int KC = (K <= 128) ? K : 128;
    __shared__ float As[32][KC + 1];
    __shared__ float Ws[KC * 64];
    const int tid = threadIdx.x;
    const size_t row0 = (size_t)blockIdx.x * 32;
    const int tx = tid & 15, ty = tid >> 4;
    const int c0 = tx * 4, r0 = ty * 2;

    for (int nc0 = 0; nc0 < N; nc0 += 64) {
        float acc[2][4] = {{0.f, 0.f, 0.f, 0.f}, {0.f, 0.f, 0.f, 0.f}};
        for (int kc0 = 0; kc0 < K; kc0 += KC) {
            __syncthreads();
            for (int idx = tid; idx < 32 * KC / 4; idx += 256) {
                int r = idx / (KC / 4);
                int kk = (idx % (KC / 4)) * 4;
                float4 v = *(const float4*)(A + (row0 + r) * K + kc0 + kk);
                As[r][kk] = v.x; As[r][kk + 1] = v.y;
                As[r][kk + 2] = v.z; As[r][kk + 3] = v.w;
            }
            for (int idx = tid; idx < KC * 16; idx += 256) {
                int k = idx >> 4;
                int cc = (idx & 15) * 4;
                *(float4*)&Ws[k * 64 + cc] =
                    *(const float4*)(W + (size_t)(kc0 + k) * N + nc0 + cc);
            }
            __syncthreads();
#pragma unroll 4
            for (int k = 0; k < KC; ++k) {
                float a0 = As[r0][k], a1 = As[r0 + 1][k];
                float4 w = *(const float4*)&Ws[k * 64 + c0];
                acc[0][0] += a0 * w.x; acc[0][1] += a0 * w.y;
                acc[0][2] += a0 * w.z; acc[0][3] += a0 * w.w;
                acc[1][0] += a1 * w.x; acc[1][1] += a1 * w.y;
                acc[1][2] += a1 * w.z; acc[1][3] += a1 * w.w;
            }
        }
#pragma unroll
        for (int i = 0; i < 2; ++i) {
            size_t off = (row0 + r0 + i) * N + nc0 + c0;
            float4 v = make_float4(acc[i][0], acc[i][1], acc[i][2], acc[i][3]);
            if (bias) {
                float4 b = *(const float4*)(bias + nc0 + c0);
                v.x += b.x; v.y += b.y; v.z += b.z; v.w += b.w;
            }
            if (act) {
                v.x = silu_f(v.x); v.y = silu_f(v.y);
                v.z = silu_f(v.z); v.w = silu_f(v.w);
            }
            if (out) *(float4*)(out + off) = v;
            if (outb) {
                ushort4 u = make_ushort4(f2b(v.x), f2b(v.y), f2b(v.z), f2b(v.w));
                *(ushort4*)(outb + off) = u;
            }
        }
    }
}

__global__ void combine_rbf(const float* __restrict__ W1, const float* __restrict__ W2,
                            float* __restrict__ C) {
    int l = blockIdx.x;
    const float* w1 = W1 + l * 48;
    const float* w2 = W2 + l * 1024;
    float* c = C + l * 768;
    for (int idx = threadIdx.x; idx < 768; idx += 256) {
        int j = idx >> 7, h = idx & 127;
        float s = 0.f;
#pragma unroll
        for (int p = 0; p < 8; ++p) s += w1[j * 8 + p] * w2[p * 128 + h];
        c[idx] = s;
    }
}

// ------------------------- CSR build -------------------------
__global__ void hist_kernel(const int* __restrict__ idx, int n, int* __restrict__ cnt) {
    int t = blockIdx.x * 256 + threadIdx.x;
    if (t < n) atomicAdd(&cnt[idx[t]], 1);
}

__launch_bounds__(1024)
__global__ void scan1(const int* __restrict__ cnt, int n, int* __restrict__ offs,
                      int* __restrict__ partials) {
    __shared__ int tmp[1024];
    int tid = threadIdx.x;
    int i = blockIdx.x * 1024 + tid;
    int v = (i < n) ? cnt[i] : 0;
    tmp[tid] = v; __syncthreads();
    for (int d = 1; d < 1024; d <<= 1) {
        int t = (tid >= d) ? tmp[tid - d] : 0; __syncthreads();
        tmp[tid] += t; __syncthreads();
    }
    if (i < n) offs[i] = tmp[tid] - v;
    if (tid == 1023) partials[blockIdx.x] = tmp[1023];
}

__launch_bounds__(1024)
__global__ void scan2(int* __restrict__ partials, int nb, int n, int* __restrict__ offs) {
    __shared__ int tmp[1024];
    int tid = threadIdx.x;
    int v = (tid < nb) ? partials[tid] : 0;
    tmp[tid] = v; __syncthreads();
    for (int d = 1; d < 1024; d <<= 1) {
        int t = (tid >= d) ? tmp[tid - d] : 0; __syncthreads();
        tmp[tid] += t; __syncthreads();
    }
    if (tid < nb) partials[tid] = tmp[tid] - v;
    if (tid == 1023) offs[n] = tmp[1023];
}

__launch_bounds__(1024)
__global__ void scan3(int n, int* __restrict__ offs, const int* __restrict__ partials,
                      int* __restrict__ cur) {
    int i = blockIdx.x * 1024 + threadIdx.x;
    if (i < n) { int o = offs[i] + partials[blockIdx.x]; offs[i] = o; cur[i] = o; }
}

__global__ void fill_kernel(const int* __restrict__ idx, int n,
                            int* __restrict__ cur, int* __restrict__ lst) {
    int t = blockIdx.x * 256 + threadIdx.x;
    if (t < n) {
        int p = atomicAdd(&cur[idx[t]], 1);
        lst[p] = t;
    }
}

// ------------------------ triplet stage ------------------------
__launch_bounds__(128)
__global__ void p8_kernel(const float* __restrict__ sbf, const float* __restrict__ W1,
                          float* __restrict__ p8) {
    __shared__ float S[128 * 43];
    __shared__ float Wl[SBF_DIM * 8];
    int tid = threadIdx.x;
    for (int i = tid; i < SBF_DIM * 8; i += 128) Wl[i] = W1[i];
    size_t base = (size_t)blockIdx.x * 128;
    int rows = (TT - base) < 128 ? (int)(TT - base) : 128;
    const float* src = sbf + base * SBF_DIM;
    for (int i = tid; i < rows * SBF_DIM; i += 128) {
        int r = i / SBF_DIM, j = i - r * SBF_DIM;
        S[r * 43 + j] = src[i];
    }
    __syncthreads();
    if (tid >= rows) return;
    float pv[8] = {0.f, 0.f, 0.f, 0.f, 0.f, 0.f, 0.f, 0.f};
    for (int j = 0; j < SBF_DIM; ++j) {
        float sv = S[tid * 43 + j];
#pragma unroll
        for (int p = 0; p < 8; ++p) pv[p] += sv * Wl[j * 8 + p];
    }
    float4* o = (float4*)(p8 + (base + tid) * 8);
    o[0] = make_float4(pv[0], pv[1], pv[2], pv[3]);
    o[1] = make_float4(pv[4], pv[5], pv[6], pv[7]);
}

__launch_bounds__(256)
__global__ void triplet_gather(const float* __restrict__ p8, const float* __restrict__ W2,
                               const unsigned short* __restrict__ xkj,
                               const int* __restrict__ idx_kj,
                               const int* __restrict__ offsT, const int* __restrict__ tlist,
                               unsigned short* __restrict__ agg) {
    int lane = threadIdx.x & 63;
    int wv = threadIdx.x >> 6;
    int e = blockIdx.x * 4 + wv;
    if (e >= EE) return;
    float w2c[8];
#pragma unroll
    for (int p = 0; p < 8; ++p) w2c[p] = W2[p * INTD + lane];
    int b = offsT[e], en = offsT[e + 1];
    float acc = 0.f;
    for (int q = b; q < en; ++q) {
        int t = tlist[q];
        int k = idx_kj[t];
        const float4* pr = (const float4*)(p8 + (size_t)t * 8);
        float4 p0 = pr[0], p1 = pr[1];
        float s = p0.x * w2c[0] + p0.y * w2c[1] + p0.z * w2c[2] + p0.w * w2c[3]
                + p1.x * w2c[4] + p1.y * w2c[5] + p1.z * w2c[6] + p1.w * w2c[7];
        acc += s * b2f(xkj[(size_t)k * INTD + lane]);
    }
    agg[(size_t)e * INTD + lane] = f2b(acc);
}

__launch_bounds__(256)
__global__ void e2_gather(const float* __restrict__ rbf, const float* __restrict__ Wr,
                          const float* __restrict__ e1f, const int* __restrict__ offsE,
                          const int* __restrict__ elist, float* __restrict__ vseg) {
    int h = threadIdx.x & 127;
    int sub = threadIdx.x >> 7;
    int n = blockIdx.x * 2 + sub;
    if (n >= NN) return;
    float c0 = Wr[0 * 128 + h], c1 = Wr[1 * 128 + h], c2 = Wr[2 * 128 + h],
          c3 = Wr[3 * 128 + h], c4 = Wr[4 * 128 + h], c5 = Wr[5 * 128 + h];
    int b = offsE[n], en = offsE[n + 1];
    float acc = 0.f;
    for (int q = b; q < en; ++q) {
        int e = elist[q];
        const float* rr = rbf + (size_t)e * NRAD;
        float r = rr[0] * c0 + rr[1] * c1 + rr[2] * c2 + rr[3] * c3 + rr[4] * c4 + rr[5] * c5;
        acc += r * e1f[(size_t)e * 128 + h];
    }
    vseg[(size_t)n * 128 + h] = acc;
}

__global__ void scatter_u0(const float* __restrict__ v, const int* __restrict__ batch,
                           float* __restrict__ u0) {
    int idx = blockIdx.x * 256 + threadIdx.x;
    int h = idx & 127;
    int n = idx >> 7;
    atomicAdd(&u0[(size_t)batch[n] * 128 + h], v[idx]);
}

__launch_bounds__(256)
__global__ void vout_scatter(const float* __restrict__ vn, const float* __restrict__ Wv_out,
                             const int* __restrict__ batch, float* __restrict__ sbatch) {
    int wave = threadIdx.x >> 6, lane = threadIdx.x & 63;
    int n = blockIdx.x * 4 + wave;
    if (n >= NN) return;
    const float* row = vn + (size_t)n * OUT_EMB;
    float s = 0.f;
#pragma unroll
    for (int k = lane; k < OUT_EMB; k += 64) s += row[k] * Wv_out[k];
#pragma unroll
    for (int off = 32; off > 0; off >>= 1) s += __shfl_down(s, off);
    if (lane == 0) atomicAdd(&sbatch[batch[n]], s);
}

__global__ void final_out(const float* __restrict__ u0, const float* __restrict__ sb,
                          float* __restrict__ out) {
    int idx = blockIdx.x * 256 + threadIdx.x;
    out[idx] = u0[idx] + sb[idx >> 7];
}

extern "C" void kernel_launch(void* const* d_in, const int* in_sizes, int n_in,
                              void* d_out, int out_size, void* d_ws, size_t ws_size,
                              hipStream_t stream) {
    const float* x         = (const float*)d_in[0];
    const float* edge_attr = (const float*)d_in[1];
    const float* rbf       = (const float*)d_in[2];
    const float* sbf       = (const float*)d_in[3];
    const int*   iidx      = (const int*)d_in[4];
    const int*   idx_kj    = (const int*)d_in[5];
    const int*   idx_ji    = (const int*)d_in[6];
    const int*   batch     = (const int*)d_in[7];
    const float* W_node    = (const float*)d_in[8];
    const float* W_edge    = (const float*)d_in[9];
    const float* We_rbf1   = (const float*)d_in[10];
    const float* We_rbf2   = (const float*)d_in[11];
    const float* We_sbf1   = (const float*)d_in[12];
    const float* We_sbf2   = (const float*)d_in[13];
    const float* We_rbf    = (const float*)d_in[14];
    const float* We_kj     = (const float*)d_in[15];
    const float* be_kj     = (const float*)d_in[16];
    const float* We_ji     = (const float*)d_in[17];
    const float* be_ji     = (const float*)d_in[18];
    const float* We_down   = (const float*)d_in[19];
    const float* We_up     = (const float*)d_in[20];
    const float* We_cat    = (const float*)d_in[21];
    const float* Wres_b    = (const float*)d_in[22];
    const float* bres_b    = (const float*)d_in[23];
    const float* We_lin    = (const float*)d_in[24];
    const float* be_lin    = (const float*)d_in[25];
    const float* Wres_a    = (const float*)d_in[26];
    const float* bres_a    = (const float*)d_in[27];
    const float* Wv_up     = (const float*)d_in[28];
    const float* bv_up     = (const float*)d_in[29];
    const float* Wv_lins   = (const float*)d_in[30];
    const float* bv_lins   = (const float*)d_in[31];
    const float* Wv_out    = (const float*)d_in[32];
    float* out = (float*)d_out;

    // ---- workspace layout ----
    unsigned short* e1b  = (unsigned short*)d_ws;            // E*128 bf16
    unsigned short* buf1 = e1b  + (size_t)EE * HH;           // E*128 bf16 (x_ji)
    unsigned short* scr2 = buf1 + (size_t)EE * HH;           // E*128 slot (p8 alias)
    unsigned short* bufC = scr2 + (size_t)EE * HH;           // E*64 bf16 (xkj_down)
    unsigned short* bufD = bufC + (size_t)EE * INTD;         // E*64 bf16 (agg)
    unsigned short* endu = bufD + (size_t)EE * INTD;
    float* e1f    = (float*)endu;                            // E*128 fp32 master
    float* tail   = e1f + (size_t)EE * HH;
    float* u0     = tail;                                    // B*128
    float* sbatch = u0 + BB * HH;                            // 256
    float* Crbf   = sbatch + 256;                            // 4*768
    int*   iptr   = (int*)(Crbf + 4 * 768);
    int* cntT  = iptr;               iptr += EE;
    int* offsT = iptr;               iptr += EE + 1;
    int* curT  = iptr;               iptr += EE;
    int* tlist = iptr;               iptr += TT;
    int* cntE  = iptr;               iptr += NN;
    int* offsE = iptr;               iptr += NN + 1;
    int* curE  = iptr;               iptr += NN;
    int* elist = iptr;               iptr += EE;
    int* partials = iptr;            iptr += 1024;
    unsigned short* wptr = (unsigned short*)iptr;
    unsigned short* wt_ji   = wptr;  wptr += 4 * 16384;
    unsigned short* wt_kj   = wptr;  wptr += 4 * 16384;
    unsigned short* wt_down = wptr;  wptr += 4 * 8192;
    unsigned short* wt_up   = wptr;  wptr += 4 * 8192;
    unsigned short* wt_cat  = wptr;  wptr += 4 * 16384;
    unsigned short* wt_resb = wptr;  wptr += 8 * 16384;
    unsigned short* wt_lin  = wptr;  wptr += 4 * 16384;
    unsigned short* wt_resa = wptr;  wptr += 16 * 16384;
    float* p8 = (float*)scr2;                                // [T,8] fp32
    float* vseg = (float*)bufC;                              // N*128 fp32 (post-MK2)
    float* vn1  = vseg + (size_t)NN * HH;                    // N*256
    float* vn2  = vn1 + (size_t)NN * OUT_EMB;                // N*256

    hipMemsetAsync(u0, 0, (size_t)BB * HH * sizeof(float), stream);
    hipMemsetAsync(sbatch, 0, 256 * sizeof(float), stream);
    combine_rbf<<<4, 256, 0, stream>>>(We_rbf1, We_rbf2, Crbf);

    transpose_w<<<(4 * 16384 + 255) / 256, 256, 0, stream>>>(We_ji, wt_ji, 4, 128, 128);
    transpose_w<<<(4 * 16384 + 255) / 256, 256, 0, stream>>>(We_kj, wt_kj, 4, 128, 128);
    transpose_w<<<(4 * 8192 + 255) / 256, 256, 0, stream>>>(We_down, wt_down, 4, 128, 64);
    transpose_w<<<(4 * 8192 + 255) / 256, 256, 0, stream>>>(We_up, wt_up, 4, 64, 128);
    transpose_w<<<(4 * 16384 + 255) / 256, 256, 0, stream>>>(We_cat, wt_cat, 4, 128, 128);
    transpose_w<<<(8 * 16384 + 255) / 256, 256, 0, stream>>>(Wres_b, wt_resb, 8, 128, 128);
    transpose_w<<<(4 * 16384 + 255) / 256, 256, 0, stream>>>(We_lin, wt_lin, 4, 128, 128);
    transpose_w<<<(16 * 16384 + 255) / 256, 256, 0, stream>>>(Wres_a, wt_resa, 16, 128, 128);

    hipMemsetAsync(cntT, 0, EE * sizeof(int), stream);
    hipMemsetAsync(cntE, 0, NN * sizeof(int), stream);
    hist_kernel<<<(TT + 255) / 256, 256, 0, stream>>>(idx_ji, TT, cntT);
    hist_kernel<<<(EE + 255) / 256, 256, 0, stream>>>(iidx, EE, cntE);
    int nbT = (EE + 1023) / 1024, nbE = (NN + 1023) / 1024;
    scan1<<<nbT, 1024, 0, stream>>>(cntT, EE, offsT, partials);
    scan2<<<1, 1024, 0, stream>>>(partials, nbT, EE, offsT);
    scan3<<<nbT, 1024, 0, stream>>>(EE, offsT, partials, curT);
    fill_kernel<<<(TT + 255) / 256, 256, 0, stream>>>(idx_ji, TT, curT, tlist);
    scan1<<<nbE, 1024, 0, stream>>>(cntE, NN, offsE, partials);
    scan2<<<1, 1024, 0, stream>>>(partials, nbE, NN, offsE);
    scan3<<<nbE, 1024, 0, stream>>>(NN, offsE, partials, curE);
    fill_kernel<<<(EE + 255) / 256, 256, 0, stream>>>(iidx, EE, curE, elist);

    gemm_k<12><<<EE / 32, 256, 0, stream>>>(edge_attr, W_edge, nullptr, e1f, e1b, HH, 0);
    gemm_k<48><<<NN / 32, 256, 0, stream>>>(x, W_node, nullptr, vseg, nullptr, HH, 0);
    scatter_u0<<<NN * HH / 256, 256, 0, stream>>>(vseg, batch, u0);

    const int GR = EE / 128;  // 3125
    for (int l = 0; l < 4; ++l) {
        mk1<<<GR, 256, 0, stream>>>(e1b, wt_ji + l * 16384, wt_kj + l * 16384,
                                    wt_down + l * 8192, be_ji + l * HH, be_kj + l * HH,
                                    rbf, Crbf + l * 768, buf1, bufC);
        p8_kernel<<<(TT + 127) / 128, 128, 0, stream>>>(sbf, We_sbf1 + l * SBF_DIM * 8, p8);
        triplet_gather<<<EE / 4, 256, 0, stream>>>(p8, We_sbf2 + l * 8 * INTD, bufC,
                                                   idx_kj, offsT, tlist, bufD);
        mk2<<<GR, 256, 0, stream>>>(bufD, buf1, e1f, e1b,
            wt_up + l * 8192, wt_cat + l * 16384,
            wt_resb + (l * 2 + 0) * 16384, wt_resb + (l * 2 + 1) * 16384,
            wt_lin + l * 16384,
            wt_resa + ((l * 2 + 0) * 2 + 0) * 16384, wt_resa + ((l * 2 + 0) * 2 + 1) * 16384,
            wt_resa + ((l * 2 + 1) * 2 + 0) * 16384, wt_resa + ((l * 2 + 1) * 2 + 1) * 16384,
            bres_b + (l * 2 + 0) * HH, bres_b + (l * 2 + 1) * HH, be_lin + l * HH,
            bres_a + ((l * 2 + 0) * 2 + 0) * HH, bres_a + ((l * 2 + 0) * 2 + 1) * HH,
            bres_a + ((l * 2 + 1) * 2 + 0) * HH, bres_a + ((l * 2 + 1) * 2 + 1) * HH);
        e2_gather<<<(NN + 1) / 2, 256, 0, stream>>>(rbf, We_rbf + (size_t)l * NRAD * HH,
                                                    e1f, offsE, elist, vseg);
        gemm_k<128><<<NN / 32, 256, 0, stream>>>(vseg, Wv_up + (size_t)l * HH * OUT_EMB,
                                                 bv_up + l * OUT_EMB, vn1, nullptr, OUT_EMB, 0);
        gemm_k<256><<<NN / 32, 256, 0, stream>>>(vn1, Wv_lins + (size_t)(l * 3 + 0) * 65536,
                                                 bv_lins + (l * 3 + 0) * 256, vn2, nullptr, OUT_EMB, 1);
        gemm_k<256><<<NN / 32, 256, 0, stream>>>(vn2, Wv_lins + (size_t)(l * 3 + 1) * 65536,
                                                 bv_lins + (l * 3 + 1) * 256, vn1, nullptr, OUT_EMB, 1);
        gemm_k<256><<<NN / 32, 256, 0, stream>>>(vn1, Wv_lins + (size_t)(l * 3 + 2) * 65536,
                                                 bv_lins + (l * 3 + 2) * 256, vn2, nullptr, OUT_EMB, 1);
        vout_scatter<<<NN / 4, 256, 0, stream>>>(vn2, Wv_out + l * OUT_EMB, batch, sbatch);
    }
    final_out<<<BB * HH / 256, 256, 0, stream>>>(u0, sbatch, out);
}